// Round 1
// baseline (1327.599 us; speedup 1.0000x reference)
//
#include <hip/hip_runtime.h>

// AttentionBlock: GN(32 groups) -> q,k,v 1x1 conv -> softmax(qk^T/sqrt(C)) v -> proj + residual
// B=8, C=512, H=W=64 (N=4096 tokens). All GEMMs as bf16 MFMA GEMM_BT.
//
// Workspace layout (~237 MiB):
//   stats[256*2] f32, wq/wk/wv/wp bf16 (512KB ea), h_nc [B*N,C] bf16 (32MiB),
//   Q [B*N,C] 32MiB, K 32MiB, Vt [B,C,N] 32MiB, O [B,N,C] 32MiB, S [4096,4096] f32 64MiB (per-batch reuse)

typedef __attribute__((ext_vector_type(8))) __bf16 bf16x8;
typedef __attribute__((ext_vector_type(4))) __bf16 bf16x4;
typedef __attribute__((ext_vector_type(4))) float f32x4;
typedef unsigned int u32;

#define DEVICE __device__ __forceinline__

DEVICE void async_copy16(const void* g, void* l) {
  __builtin_amdgcn_global_load_lds(
      (__attribute__((address_space(1))) u32*)(g),
      (__attribute__((address_space(3))) u32*)(l),
      16, 0, 0);
}

// ---------------------------------------------------------------- weights->bf16
__global__ __launch_bounds__(256) void cvt_w(
    const float* __restrict__ w0, const float* __restrict__ w1,
    const float* __restrict__ w2, const float* __restrict__ w3,
    __bf16* __restrict__ o0, __bf16* __restrict__ o1,
    __bf16* __restrict__ o2, __bf16* __restrict__ o3) {
  int idx = blockIdx.x * 256 + threadIdx.x;   // 131072 threads, 8 elems each
  int off = idx * 8;
  int m = off >> 18;            // 262144 elems per matrix
  int r = off & 262143;
  const float* src = m == 0 ? w0 : m == 1 ? w1 : m == 2 ? w2 : w3;
  __bf16* dst = m == 0 ? o0 : m == 1 ? o1 : m == 2 ? o2 : o3;
  float4 a = *(const float4*)(src + r);
  float4 b = *(const float4*)(src + r + 4);
  bf16x8 v = {(__bf16)a.x, (__bf16)a.y, (__bf16)a.z, (__bf16)a.w,
              (__bf16)b.x, (__bf16)b.y, (__bf16)b.z, (__bf16)b.w};
  *(bf16x8*)(dst + r) = v;
}

// ---------------------------------------------------------------- groupnorm stats
__global__ __launch_bounds__(256) void gn_stats(const float* __restrict__ x,
                                                float* __restrict__ stats) {
  int bg = blockIdx.x;                       // b*32+g, 256 blocks
  const float* p = x + (size_t)bg * 65536;   // 16 ch * 4096
  int t = threadIdx.x, lane = t & 63, w = t >> 6;
  float s = 0.f, ss = 0.f;
  for (int i = t; i < 16384; i += 256) {
    float4 v = *(const float4*)(p + i * 4);
    s += v.x + v.y + v.z + v.w;
    ss += v.x * v.x + v.y * v.y + v.z * v.z + v.w * v.w;
  }
#pragma unroll
  for (int off = 32; off; off >>= 1) {
    s += __shfl_xor(s, off);
    ss += __shfl_xor(ss, off);
  }
  __shared__ float rs_[4], rss_[4];
  if (lane == 0) { rs_[w] = s; rss_[w] = ss; }
  __syncthreads();
  if (t == 0) {
    float S = rs_[0] + rs_[1] + rs_[2] + rs_[3];
    float SS = rss_[0] + rss_[1] + rss_[2] + rss_[3];
    float mean = S * (1.0f / 65536.0f);
    float var = SS * (1.0f / 65536.0f) - mean * mean;
    stats[bg * 2] = mean;
    stats[bg * 2 + 1] = rsqrtf(var + 1e-5f);
  }
}

// ---------------------------------------------------------------- groupnorm apply + transpose to [B,N,C] bf16
__global__ __launch_bounds__(256) void gn_apply(
    const float* __restrict__ x, const float* __restrict__ gamma,
    const float* __restrict__ beta, const float* __restrict__ stats,
    __bf16* __restrict__ h) {
  int b = blockIdx.z, g = blockIdx.y;
  int n = blockIdx.x * 256 + threadIdx.x;
  const float* px = x + ((size_t)b * 512 + g * 16) * 4096 + n;
  float mean = stats[(b * 32 + g) * 2];
  float rstd = stats[(b * 32 + g) * 2 + 1];
  bf16x8 lo, hi;
#pragma unroll
  for (int c = 0; c < 8; ++c) {
    float v = px[(size_t)c * 4096];
    lo[c] = (__bf16)((v - mean) * rstd * gamma[g * 16 + c] + beta[g * 16 + c]);
  }
#pragma unroll
  for (int c = 0; c < 8; ++c) {
    float v = px[(size_t)(c + 8) * 4096];
    hi[c] = (__bf16)((v - mean) * rstd * gamma[g * 16 + c + 8] + beta[g * 16 + c + 8]);
  }
  __bf16* dst = h + ((size_t)b * 4096 + n) * 512 + g * 16;
  *(bf16x8*)dst = lo;
  *(bf16x8*)(dst + 8) = hi;
}

// ---------------------------------------------------------------- GEMM_BT
// C[m,n] = sum_k A[m,k]*B[n,k]  (A:[M,K] lda, B:[N,K] ldb, both bf16)
// 128x128 tile, BK=32, 256 thr = 4 waves (2x2), wave tile 64x64 = 4x4 mfma frags.
// EPI: 0 bf16 + colbias | 1 bf16 + rowbias | 2 f32 raw | 3 f32 + rowbias + resid | 4 bf16 plain
template <int EPI>
__global__ __launch_bounds__(256) void gemm_bt(
    const __bf16* __restrict__ A, const __bf16* __restrict__ B,
    void* __restrict__ Cout, int K, int lda, int ldb, int ldc,
    const float* __restrict__ bias, const float* __restrict__ resid,
    long sA, long sB, long sC, long sR) {
  int z = blockIdx.z;
  A += (size_t)z * sA;
  B += (size_t)z * sB;
  __shared__ __bf16 lA[128 * 32];
  __shared__ __bf16 lB[128 * 32];
  int t = threadIdx.x, lane = t & 63, w = t >> 6;
  int row0 = blockIdx.x * 128, col0 = blockIdx.y * 128;
  int wr = w >> 1, wc = w & 1;
  f32x4 acc[4][4] = {};

  for (int k0 = 0; k0 < K; k0 += 32) {
    __syncthreads();  // previous tile fully consumed
#pragma unroll
    for (int r = 0; r < 2; ++r) {
      int chunk = r * 256 + w * 64 + lane;
      int row = chunk >> 2, cc = (chunk & 3) << 3;
      async_copy16(A + (size_t)(row0 + row) * lda + k0 + cc,
                   lA + (r * 256 + w * 64) * 8);
    }
#pragma unroll
    for (int r = 0; r < 2; ++r) {
      int chunk = r * 256 + w * 64 + lane;
      int row = chunk >> 2, cc = (chunk & 3) << 3;
      async_copy16(B + (size_t)(col0 + row) * ldb + k0 + cc,
                   lB + (r * 256 + w * 64) * 8);
    }
    __syncthreads();  // staging visible (compiler drains vmcnt before barrier)
    bf16x8 af[4], bf[4];
    int kk = (lane >> 4) * 8;
#pragma unroll
    for (int i = 0; i < 4; ++i) {
      af[i] = *(const bf16x8*)(lA + (wr * 64 + i * 16 + (lane & 15)) * 32 + kk);
      bf[i] = *(const bf16x8*)(lB + (wc * 64 + i * 16 + (lane & 15)) * 32 + kk);
    }
#pragma unroll
    for (int i = 0; i < 4; ++i)
#pragma unroll
      for (int j = 0; j < 4; ++j)
        acc[i][j] = __builtin_amdgcn_mfma_f32_16x16x32_bf16(af[i], bf[j], acc[i][j], 0, 0, 0);
  }

  // epilogue: C/D layout col=lane&15, row=(lane>>4)*4+reg  [m89-verified]
  int rbase = row0 + wr * 64, cbase = col0 + wc * 64;
#pragma unroll
  for (int i = 0; i < 4; ++i) {
#pragma unroll
    for (int j = 0; j < 4; ++j) {
      int col = cbase + j * 16 + (lane & 15);
#pragma unroll
      for (int rg = 0; rg < 4; ++rg) {
        int row = rbase + i * 16 + (lane >> 4) * 4 + rg;
        float v = acc[i][j][rg];
        size_t idx = (size_t)z * sC + (size_t)row * ldc + col;
        if constexpr (EPI == 0) {
          ((__bf16*)Cout)[idx] = (__bf16)(v + bias[col]);
        } else if constexpr (EPI == 1) {
          ((__bf16*)Cout)[idx] = (__bf16)(v + bias[row]);
        } else if constexpr (EPI == 2) {
          ((float*)Cout)[idx] = v;
        } else if constexpr (EPI == 3) {
          ((float*)Cout)[idx] =
              v + bias[row] + resid[(size_t)z * sR + (size_t)row * ldc + col];
        } else {
          ((__bf16*)Cout)[idx] = (__bf16)v;
        }
      }
    }
  }
}

// ---------------------------------------------------------------- row softmax, in-place S(f32) -> P(bf16)
// P row i reuses S row i's own storage (first 8KB of the 16KB row), so no cross-row hazard.
__global__ __launch_bounds__(256) void softmax_rows(float* __restrict__ S) {
  int row = blockIdx.x;
  float* p = S + (size_t)row * 4096;
  int t = threadIdx.x, lane = t & 63, w = t >> 6;
  const float c1 = 0.04419417382415922f * 1.4426950408889634f;  // (1/sqrt(512))*log2(e)
  float4 v[4];
  float mx = -3.4e38f;
#pragma unroll
  for (int r = 0; r < 4; ++r) {
    v[r] = *(const float4*)(p + (r * 256 + t) * 4);
    mx = fmaxf(fmaxf(fmaxf(v[r].x, v[r].y), fmaxf(v[r].z, v[r].w)), mx);
  }
#pragma unroll
  for (int off = 32; off; off >>= 1) mx = fmaxf(mx, __shfl_xor(mx, off));
  __shared__ float rm[4], rsum[4];
  if (lane == 0) rm[w] = mx;
  __syncthreads();
  float m = fmaxf(fmaxf(rm[0], rm[1]), fmaxf(rm[2], rm[3]));
  float pv[16];
  float s = 0.f;
#pragma unroll
  for (int r = 0; r < 4; ++r) {
    pv[r * 4 + 0] = exp2f((v[r].x - m) * c1);
    pv[r * 4 + 1] = exp2f((v[r].y - m) * c1);
    pv[r * 4 + 2] = exp2f((v[r].z - m) * c1);
    pv[r * 4 + 3] = exp2f((v[r].w - m) * c1);
    s += pv[r * 4] + pv[r * 4 + 1] + pv[r * 4 + 2] + pv[r * 4 + 3];
  }
#pragma unroll
  for (int off = 32; off; off >>= 1) s += __shfl_xor(s, off);
  if (lane == 0) rsum[w] = s;
  __syncthreads();
  float inv = 1.0f / (rsum[0] + rsum[1] + rsum[2] + rsum[3]);
  __bf16* dst = (__bf16*)S + (size_t)row * 8192;  // same bytes as this row's f32 storage
#pragma unroll
  for (int r = 0; r < 4; ++r) {
    bf16x4 o4 = {(__bf16)(pv[r * 4] * inv), (__bf16)(pv[r * 4 + 1] * inv),
                 (__bf16)(pv[r * 4 + 2] * inv), (__bf16)(pv[r * 4 + 3] * inv)};
    *(bf16x4*)(dst + (r * 256 + t) * 4) = o4;
  }
}

// ---------------------------------------------------------------- launch
extern "C" void kernel_launch(void* const* d_in, const int* in_sizes, int n_in,
                              void* d_out, int out_size, void* d_ws, size_t ws_size,
                              hipStream_t stream) {
  const float* x = (const float*)d_in[0];
  const float* gamma = (const float*)d_in[1];
  const float* beta = (const float*)d_in[2];
  const float* wq = (const float*)d_in[3];
  const float* bq = (const float*)d_in[4];
  const float* wk = (const float*)d_in[5];
  const float* bk = (const float*)d_in[6];
  const float* wv = (const float*)d_in[7];
  const float* bv = (const float*)d_in[8];
  const float* wp = (const float*)d_in[9];
  const float* bp = (const float*)d_in[10];

  char* p = (char*)d_ws;
  auto alloc = [&](size_t bytes) {
    char* r = p;
    p += (bytes + 255) & ~(size_t)255;
    return r;
  };
  float* stats = (float*)alloc(256 * 2 * 4);
  __bf16* wqb = (__bf16*)alloc(512 * 512 * 2);
  __bf16* wkb = (__bf16*)alloc(512 * 512 * 2);
  __bf16* wvb = (__bf16*)alloc(512 * 512 * 2);
  __bf16* wpb = (__bf16*)alloc(512 * 512 * 2);
  __bf16* h = (__bf16*)alloc((size_t)8 * 4096 * 512 * 2);   // [B*N, C]
  __bf16* q = (__bf16*)alloc((size_t)8 * 4096 * 512 * 2);   // [B*N, C]
  __bf16* kb = (__bf16*)alloc((size_t)8 * 4096 * 512 * 2);  // [B*N, C]
  __bf16* vt = (__bf16*)alloc((size_t)8 * 512 * 4096 * 2);  // [B, C, N]
  __bf16* o = (__bf16*)alloc((size_t)8 * 4096 * 512 * 2);   // [B, N, C]
  float* s = (float*)alloc((size_t)4096 * 4096 * 4);        // per-batch S / in-place P

  cvt_w<<<512, 256, 0, stream>>>(wq, wk, wv, wp, wqb, wkb, wvb, wpb);
  gn_stats<<<256, 256, 0, stream>>>(x, stats);
  gn_apply<<<dim3(16, 32, 8), 256, 0, stream>>>(x, gamma, beta, stats, h);

  // Q = h x Wq^T  [32768,512]
  gemm_bt<0><<<dim3(256, 4, 1), 256, 0, stream>>>(h, wqb, q, 512, 512, 512, 512,
                                                  bq, nullptr, 0, 0, 0, 0);
  gemm_bt<0><<<dim3(256, 4, 1), 256, 0, stream>>>(h, wkb, kb, 512, 512, 512, 512,
                                                  bk, nullptr, 0, 0, 0, 0);
  // Vt[b] = Wv x h[b]^T  [512, 4096] per batch
  gemm_bt<1><<<dim3(4, 32, 8), 256, 0, stream>>>(wvb, h, vt, 512, 512, 512, 4096,
                                                 bv, nullptr, 0, 2097152, 2097152, 0);

  for (int b = 0; b < 8; ++b) {
    const __bf16* qb_ = q + (size_t)b * 2097152;
    const __bf16* kb_ = kb + (size_t)b * 2097152;
    const __bf16* vb_ = vt + (size_t)b * 2097152;
    __bf16* ob_ = o + (size_t)b * 2097152;
    // S = Q K^T (raw dot, f32)
    gemm_bt<2><<<dim3(32, 32, 1), 256, 0, stream>>>(qb_, kb_, (void*)s, 512, 512,
                                                    512, 4096, nullptr, nullptr,
                                                    0, 0, 0, 0);
    softmax_rows<<<4096, 256, 0, stream>>>(s);
    // O = P V   (P bf16 in-place over S, lda=8192)
    gemm_bt<4><<<dim3(32, 4, 1), 256, 0, stream>>>((const __bf16*)s, vb_, ob_,
                                                   4096, 8192, 4096, 512,
                                                   nullptr, nullptr, 0, 0, 0, 0);
  }
  // out = x + Wp x O^T + bp   -> [B, C, N] f32
  gemm_bt<3><<<dim3(4, 32, 8), 256, 0, stream>>>(
      wpb, o, d_out, 512, 512, 512, 4096, bp, x, 0, 2097152, 2097152, 2097152);
}

// Round 2
// 1326.950 us; speedup vs baseline: 1.0005x; 1.0005x over previous
//
#include <hip/hip_runtime.h>

// AttentionBlock: GN(32) -> q,k,v 1x1 -> softmax(qk^T/sqrt(C)) v -> proj + residual
// B=8, C=512, N=4096. All GEMMs bf16 MFMA GEMM_BT (m97 structure + T2 LDS swizzle).
// Attention core batched across z (adaptive chunking on ws_size).

typedef __attribute__((ext_vector_type(8))) __bf16 bf16x8;
typedef __attribute__((ext_vector_type(4))) __bf16 bf16x4;
typedef __attribute__((ext_vector_type(4))) float f32x4;
typedef unsigned int u32;

#define DEVICE __device__ __forceinline__

DEVICE void async_copy16(const void* g, void* l) {
  __builtin_amdgcn_global_load_lds(
      (__attribute__((address_space(1))) u32*)(g),
      (__attribute__((address_space(3))) u32*)(l),
      16, 0, 0);
}

// ---------------------------------------------------------------- weights->bf16
__global__ __launch_bounds__(256) void cvt_w(
    const float* __restrict__ w0, const float* __restrict__ w1,
    const float* __restrict__ w2, const float* __restrict__ w3,
    __bf16* __restrict__ o0, __bf16* __restrict__ o1,
    __bf16* __restrict__ o2, __bf16* __restrict__ o3) {
  int idx = blockIdx.x * 256 + threadIdx.x;
  int off = idx * 8;
  int m = off >> 18;
  int r = off & 262143;
  const float* src = m == 0 ? w0 : m == 1 ? w1 : m == 2 ? w2 : w3;
  __bf16* dst = m == 0 ? o0 : m == 1 ? o1 : m == 2 ? o2 : o3;
  float4 a = *(const float4*)(src + r);
  float4 b = *(const float4*)(src + r + 4);
  bf16x8 v = {(__bf16)a.x, (__bf16)a.y, (__bf16)a.z, (__bf16)a.w,
              (__bf16)b.x, (__bf16)b.y, (__bf16)b.z, (__bf16)b.w};
  *(bf16x8*)(dst + r) = v;
}

// ---------------------------------------------------------------- groupnorm stats
__global__ __launch_bounds__(256) void gn_stats(const float* __restrict__ x,
                                                float* __restrict__ stats) {
  int bg = blockIdx.x;
  const float* p = x + (size_t)bg * 65536;
  int t = threadIdx.x, lane = t & 63, w = t >> 6;
  float s = 0.f, ss = 0.f;
  for (int i = t; i < 16384; i += 256) {
    float4 v = *(const float4*)(p + i * 4);
    s += v.x + v.y + v.z + v.w;
    ss += v.x * v.x + v.y * v.y + v.z * v.z + v.w * v.w;
  }
#pragma unroll
  for (int off = 32; off; off >>= 1) {
    s += __shfl_xor(s, off);
    ss += __shfl_xor(ss, off);
  }
  __shared__ float rs_[4], rss_[4];
  if (lane == 0) { rs_[w] = s; rss_[w] = ss; }
  __syncthreads();
  if (t == 0) {
    float S = rs_[0] + rs_[1] + rs_[2] + rs_[3];
    float SS = rss_[0] + rss_[1] + rss_[2] + rss_[3];
    float mean = S * (1.0f / 65536.0f);
    float var = SS * (1.0f / 65536.0f) - mean * mean;
    stats[bg * 2] = mean;
    stats[bg * 2 + 1] = rsqrtf(var + 1e-5f);
  }
}

// ---------------------------------------------------------------- groupnorm apply + transpose to [B,N,C] bf16
__global__ __launch_bounds__(256) void gn_apply(
    const float* __restrict__ x, const float* __restrict__ gamma,
    const float* __restrict__ beta, const float* __restrict__ stats,
    __bf16* __restrict__ h) {
  int b = blockIdx.z, g = blockIdx.y;
  int n = blockIdx.x * 256 + threadIdx.x;
  const float* px = x + ((size_t)b * 512 + g * 16) * 4096 + n;
  float mean = stats[(b * 32 + g) * 2];
  float rstd = stats[(b * 32 + g) * 2 + 1];
  bf16x8 lo, hi;
#pragma unroll
  for (int c = 0; c < 8; ++c) {
    float v = px[(size_t)c * 4096];
    lo[c] = (__bf16)((v - mean) * rstd * gamma[g * 16 + c] + beta[g * 16 + c]);
  }
#pragma unroll
  for (int c = 0; c < 8; ++c) {
    float v = px[(size_t)(c + 8) * 4096];
    hi[c] = (__bf16)((v - mean) * rstd * gamma[g * 16 + c + 8] + beta[g * 16 + c + 8]);
  }
  __bf16* dst = h + ((size_t)b * 4096 + n) * 512 + g * 16;
  *(bf16x8*)dst = lo;
  *(bf16x8*)(dst + 8) = hi;
}

// ---------------------------------------------------------------- GEMM_BT
// C[m,n] = sum_k A[m,k]*B[n,k]  (A:[M,K] lda, B:[N,K] ldb, both bf16)
// 128x128 tile, BK=32, 4 waves (2x2), wave tile 64x64 = 4x4 mfma frags.
// T2 LDS swizzle: 16B chunk c of row r lives at slot c^((r>>1)&3); applied as
// pre-swizzled GLOBAL source (linear LDS dest, rule #21) + XOR'd ds_read addr.
// EPI: 0 bf16+colbias | 1 bf16+rowbias | 2 f32 raw | 3 f32+rowbias+resid | 4 bf16
template <int EPI>
__global__ __launch_bounds__(256) void gemm_bt(
    const __bf16* __restrict__ A, const __bf16* __restrict__ B,
    void* __restrict__ Cout, int K, int lda, int ldb, int ldc,
    const float* __restrict__ bias, const float* __restrict__ resid,
    long sA, long sB, long sC, long sR) {
  int z = blockIdx.z;
  A += (size_t)z * sA;
  B += (size_t)z * sB;
  __shared__ __bf16 lA[128 * 32];
  __shared__ __bf16 lB[128 * 32];
  int t = threadIdx.x, lane = t & 63, w = t >> 6;
  int row0 = blockIdx.x * 128, col0 = blockIdx.y * 128;
  int wr = w >> 1, wc = w & 1;
  f32x4 acc[4][4] = {};

  // read-side swizzled chunk offset (constant per thread: (row>>1)&3 == ((lane&15)>>1)&3)
  int sw = ((lane & 15) >> 1) & 3;
  int ca = ((lane >> 4) ^ sw) << 3;  // element offset of the 8-elem chunk to read

  for (int k0 = 0; k0 < K; k0 += 32) {
    __syncthreads();  // previous tile fully consumed
#pragma unroll
    for (int r = 0; r < 2; ++r) {
      int chunk = r * 256 + w * 64 + lane;
      int row = chunk >> 2;
      int csrc = ((chunk & 3) ^ ((row >> 1) & 3)) << 3;  // pre-swizzled source
      async_copy16(A + (size_t)(row0 + row) * lda + k0 + csrc,
                   lA + (r * 256 + w * 64) * 8);
    }
#pragma unroll
    for (int r = 0; r < 2; ++r) {
      int chunk = r * 256 + w * 64 + lane;
      int row = chunk >> 2;
      int csrc = ((chunk & 3) ^ ((row >> 1) & 3)) << 3;
      async_copy16(B + (size_t)(col0 + row) * ldb + k0 + csrc,
                   lB + (r * 256 + w * 64) * 8);
    }
    __syncthreads();  // staging visible
    bf16x8 af[4], bf[4];
#pragma unroll
    for (int i = 0; i < 4; ++i) {
      af[i] = *(const bf16x8*)(lA + (wr * 64 + i * 16 + (lane & 15)) * 32 + ca);
      bf[i] = *(const bf16x8*)(lB + (wc * 64 + i * 16 + (lane & 15)) * 32 + ca);
    }
#pragma unroll
    for (int i = 0; i < 4; ++i)
#pragma unroll
      for (int j = 0; j < 4; ++j)
        acc[i][j] = __builtin_amdgcn_mfma_f32_16x16x32_bf16(af[i], bf[j], acc[i][j], 0, 0, 0);
  }

  // epilogue: C/D layout col=lane&15, row=(lane>>4)*4+reg  [m89-verified]
  int rbase = row0 + wr * 64, cbase = col0 + wc * 64;
#pragma unroll
  for (int i = 0; i < 4; ++i) {
#pragma unroll
    for (int j = 0; j < 4; ++j) {
      int col = cbase + j * 16 + (lane & 15);
#pragma unroll
      for (int rg = 0; rg < 4; ++rg) {
        int row = rbase + i * 16 + (lane >> 4) * 4 + rg;
        float v = acc[i][j][rg];
        size_t idx = (size_t)z * sC + (size_t)row * ldc + col;
        if constexpr (EPI == 0) {
          ((__bf16*)Cout)[idx] = (__bf16)(v + bias[col]);
        } else if constexpr (EPI == 1) {
          ((__bf16*)Cout)[idx] = (__bf16)(v + bias[row]);
        } else if constexpr (EPI == 2) {
          ((float*)Cout)[idx] = v;
        } else if constexpr (EPI == 3) {
          ((float*)Cout)[idx] =
              v + bias[row] + resid[(size_t)z * sR + (size_t)row * ldc + col];
        } else {
          ((__bf16*)Cout)[idx] = (__bf16)v;
        }
      }
    }
  }
}

// ---------------------------------------------------------------- row softmax, in-place S(f32) -> P(bf16)
__global__ __launch_bounds__(256) void softmax_rows(float* __restrict__ S) {
  int row = blockIdx.x;
  float* p = S + (size_t)row * 4096;
  int t = threadIdx.x, lane = t & 63, w = t >> 6;
  const float c1 = 0.04419417382415922f * 1.4426950408889634f;  // (1/sqrt(512))*log2(e)
  float4 v[4];
  float mx = -3.4e38f;
#pragma unroll
  for (int r = 0; r < 4; ++r) {
    v[r] = *(const float4*)(p + (r * 256 + t) * 4);
    mx = fmaxf(fmaxf(fmaxf(v[r].x, v[r].y), fmaxf(v[r].z, v[r].w)), mx);
  }
#pragma unroll
  for (int off = 32; off; off >>= 1) mx = fmaxf(mx, __shfl_xor(mx, off));
  __shared__ float rm[4], rsum[4];
  if (lane == 0) rm[w] = mx;
  __syncthreads();
  float m = fmaxf(fmaxf(rm[0], rm[1]), fmaxf(rm[2], rm[3]));
  float pv[16];
  float s = 0.f;
#pragma unroll
  for (int r = 0; r < 4; ++r) {
    pv[r * 4 + 0] = exp2f((v[r].x - m) * c1);
    pv[r * 4 + 1] = exp2f((v[r].y - m) * c1);
    pv[r * 4 + 2] = exp2f((v[r].z - m) * c1);
    pv[r * 4 + 3] = exp2f((v[r].w - m) * c1);
    s += pv[r * 4] + pv[r * 4 + 1] + pv[r * 4 + 2] + pv[r * 4 + 3];
  }
#pragma unroll
  for (int off = 32; off; off >>= 1) s += __shfl_xor(s, off);
  if (lane == 0) rsum[w] = s;
  __syncthreads();
  float inv = 1.0f / (rsum[0] + rsum[1] + rsum[2] + rsum[3]);
  __bf16* dst = (__bf16*)S + (size_t)row * 8192;  // same bytes as this row's f32 storage
#pragma unroll
  for (int r = 0; r < 4; ++r) {
    bf16x4 o4 = {(__bf16)(pv[r * 4] * inv), (__bf16)(pv[r * 4 + 1] * inv),
                 (__bf16)(pv[r * 4 + 2] * inv), (__bf16)(pv[r * 4 + 3] * inv)};
    *(bf16x4*)(dst + (r * 256 + t) * 4) = o4;
  }
}

// ---------------------------------------------------------------- launch
extern "C" void kernel_launch(void* const* d_in, const int* in_sizes, int n_in,
                              void* d_out, int out_size, void* d_ws, size_t ws_size,
                              hipStream_t stream) {
  const float* x = (const float*)d_in[0];
  const float* gamma = (const float*)d_in[1];
  const float* beta = (const float*)d_in[2];
  const float* wq = (const float*)d_in[3];
  const float* bq = (const float*)d_in[4];
  const float* wk = (const float*)d_in[5];
  const float* bk = (const float*)d_in[6];
  const float* wv = (const float*)d_in[7];
  const float* bv = (const float*)d_in[8];
  const float* wp = (const float*)d_in[9];
  const float* bp = (const float*)d_in[10];

  char* p = (char*)d_ws;
  auto alloc = [&](size_t bytes) {
    char* r = p;
    p += (bytes + 255) & ~(size_t)255;
    return r;
  };
  float* stats = (float*)alloc(256 * 2 * 4);
  __bf16* wqb = (__bf16*)alloc(512 * 512 * 2);
  __bf16* wkb = (__bf16*)alloc(512 * 512 * 2);
  __bf16* wvb = (__bf16*)alloc(512 * 512 * 2);
  __bf16* wpb = (__bf16*)alloc(512 * 512 * 2);
  __bf16* h = (__bf16*)alloc((size_t)8 * 4096 * 512 * 2);   // [B*N, C]
  __bf16* q = (__bf16*)alloc((size_t)8 * 4096 * 512 * 2);   // [B*N, C]
  __bf16* kb = (__bf16*)alloc((size_t)8 * 4096 * 512 * 2);  // [B*N, C]
  __bf16* vt = (__bf16*)alloc((size_t)8 * 512 * 4096 * 2);  // [B, C, N]
  __bf16* o = (__bf16*)alloc((size_t)8 * 4096 * 512 * 2);   // [B, N, C]

  // adaptive S chunking: as many batches of [4096,4096] f32 as ws allows
  const size_t SB = (size_t)4096 * 4096 * 4;  // 64 MiB per batch
  size_t used = (size_t)(p - (char*)d_ws);
  int nb = (ws_size > used) ? (int)((ws_size - used) / SB) : 1;
  if (nb > 8) nb = 8;
  if (nb < 1) nb = 1;
  float* s = (float*)alloc(SB * nb);

  cvt_w<<<512, 256, 0, stream>>>(wq, wk, wv, wp, wqb, wkb, wvb, wpb);
  gn_stats<<<256, 256, 0, stream>>>(x, stats);
  gn_apply<<<dim3(16, 32, 8), 256, 0, stream>>>(x, gamma, beta, stats, h);

  // Q = h Wq^T, K = h Wk^T  [32768,512]
  gemm_bt<0><<<dim3(256, 4, 1), 256, 0, stream>>>(h, wqb, q, 512, 512, 512, 512,
                                                  bq, nullptr, 0, 0, 0, 0);
  gemm_bt<0><<<dim3(256, 4, 1), 256, 0, stream>>>(h, wkb, kb, 512, 512, 512, 512,
                                                  bk, nullptr, 0, 0, 0, 0);
  // Vt[b] = Wv h[b]^T  [512,4096] per batch
  gemm_bt<1><<<dim3(4, 32, 8), 256, 0, stream>>>(wvb, h, vt, 512, 512, 512, 4096,
                                                 bv, nullptr, 0, 2097152, 2097152, 0);

  for (int b0 = 0; b0 < 8; b0 += nb) {
    int zb = (8 - b0 < nb) ? (8 - b0) : nb;
    // S = Q K^T (f32), batched over z
    gemm_bt<2><<<dim3(32, 32, zb), 256, 0, stream>>>(
        q + (size_t)b0 * 2097152, kb + (size_t)b0 * 2097152, (void*)s, 512, 512,
        512, 4096, nullptr, nullptr, 2097152, 2097152, 16777216, 0);
    softmax_rows<<<zb * 4096, 256, 0, stream>>>(s);
    // O = P V (P bf16 in-place over S, lda=8192), batched over z
    gemm_bt<4><<<dim3(32, 4, zb), 256, 0, stream>>>(
        (const __bf16*)s, vt + (size_t)b0 * 2097152, o + (size_t)b0 * 2097152,
        4096, 8192, 4096, 512, nullptr, nullptr, 33554432, 2097152, 2097152, 0);
  }
  // out = x + Wp O^T + bp  -> [B,C,N] f32
  gemm_bt<3><<<dim3(4, 32, 8), 256, 0, stream>>>(
      wpb, o, d_out, 512, 512, 512, 4096, bp, x, 0, 2097152, 2097152, 2097152);
}

// Round 3
// 862.342 us; speedup vs baseline: 1.5395x; 1.5388x over previous
//
#include <hip/hip_runtime.h>

// AttentionBlock: GN(32) -> q,k,v 1x1 -> softmax(qk^T/sqrt(C)) v -> proj + residual
// B=8, C=512, N=4096. All GEMMs bf16 MFMA GEMM_BT (m97 structure + T2 LDS swizzle).
// S stored bf16 (32 MiB/batch) so the attention core batches across z; O aliases h.

typedef __attribute__((ext_vector_type(8))) __bf16 bf16x8;
typedef __attribute__((ext_vector_type(4))) __bf16 bf16x4;
typedef __attribute__((ext_vector_type(4))) float f32x4;
typedef unsigned int u32;

#define DEVICE __device__ __forceinline__

DEVICE void async_copy16(const void* g, void* l) {
  __builtin_amdgcn_global_load_lds(
      (__attribute__((address_space(1))) u32*)(g),
      (__attribute__((address_space(3))) u32*)(l),
      16, 0, 0);
}

// ---------------------------------------------------------------- weights->bf16
__global__ __launch_bounds__(256) void cvt_w(
    const float* __restrict__ w0, const float* __restrict__ w1,
    const float* __restrict__ w2, const float* __restrict__ w3,
    __bf16* __restrict__ o0, __bf16* __restrict__ o1,
    __bf16* __restrict__ o2, __bf16* __restrict__ o3) {
  int idx = blockIdx.x * 256 + threadIdx.x;
  int off = idx * 8;
  int m = off >> 18;
  int r = off & 262143;
  const float* src = m == 0 ? w0 : m == 1 ? w1 : m == 2 ? w2 : w3;
  __bf16* dst = m == 0 ? o0 : m == 1 ? o1 : m == 2 ? o2 : o3;
  float4 a = *(const float4*)(src + r);
  float4 b = *(const float4*)(src + r + 4);
  bf16x8 v = {(__bf16)a.x, (__bf16)a.y, (__bf16)a.z, (__bf16)a.w,
              (__bf16)b.x, (__bf16)b.y, (__bf16)b.z, (__bf16)b.w};
  *(bf16x8*)(dst + r) = v;
}

// ---------------------------------------------------------------- groupnorm stats
__global__ __launch_bounds__(256) void gn_stats(const float* __restrict__ x,
                                                float* __restrict__ stats) {
  int bg = blockIdx.x;
  const float* p = x + (size_t)bg * 65536;
  int t = threadIdx.x, lane = t & 63, w = t >> 6;
  float s = 0.f, ss = 0.f;
  for (int i = t; i < 16384; i += 256) {
    float4 v = *(const float4*)(p + i * 4);
    s += v.x + v.y + v.z + v.w;
    ss += v.x * v.x + v.y * v.y + v.z * v.z + v.w * v.w;
  }
#pragma unroll
  for (int off = 32; off; off >>= 1) {
    s += __shfl_xor(s, off);
    ss += __shfl_xor(ss, off);
  }
  __shared__ float rs_[4], rss_[4];
  if (lane == 0) { rs_[w] = s; rss_[w] = ss; }
  __syncthreads();
  if (t == 0) {
    float S = rs_[0] + rs_[1] + rs_[2] + rs_[3];
    float SS = rss_[0] + rss_[1] + rss_[2] + rss_[3];
    float mean = S * (1.0f / 65536.0f);
    float var = SS * (1.0f / 65536.0f) - mean * mean;
    stats[bg * 2] = mean;
    stats[bg * 2 + 1] = rsqrtf(var + 1e-5f);
  }
}

// ---------------------------------------------------------------- groupnorm apply + transpose to [B,N,C] bf16
__global__ __launch_bounds__(256) void gn_apply(
    const float* __restrict__ x, const float* __restrict__ gamma,
    const float* __restrict__ beta, const float* __restrict__ stats,
    __bf16* __restrict__ h) {
  int b = blockIdx.z, g = blockIdx.y;
  int n = blockIdx.x * 256 + threadIdx.x;
  const float* px = x + ((size_t)b * 512 + g * 16) * 4096 + n;
  float mean = stats[(b * 32 + g) * 2];
  float rstd = stats[(b * 32 + g) * 2 + 1];
  bf16x8 lo, hi;
#pragma unroll
  for (int c = 0; c < 8; ++c) {
    float v = px[(size_t)c * 4096];
    lo[c] = (__bf16)((v - mean) * rstd * gamma[g * 16 + c] + beta[g * 16 + c]);
  }
#pragma unroll
  for (int c = 0; c < 8; ++c) {
    float v = px[(size_t)(c + 8) * 4096];
    hi[c] = (__bf16)((v - mean) * rstd * gamma[g * 16 + c + 8] + beta[g * 16 + c + 8]);
  }
  __bf16* dst = h + ((size_t)b * 4096 + n) * 512 + g * 16;
  *(bf16x8*)dst = lo;
  *(bf16x8*)(dst + 8) = hi;
}

// ---------------------------------------------------------------- GEMM_BT
// C[m,n] = sum_k A[m,k]*B[n,k]  (A:[M,K] lda, B:[N,K] ldb, both bf16)
// 128x128 tile, BK=32, 4 waves (2x2), wave tile 64x64 = 4x4 mfma frags.
// T2 LDS swizzle: 16B chunk c of row r at slot c^((r>>1)&3), both sides (rule #21).
// EPI: 0 bf16+colbias | 1 bf16+rowbias | 2 f32 raw | 3 f32+rowbias+resid | 4 bf16
template <int EPI>
__global__ __launch_bounds__(256) void gemm_bt(
    const __bf16* __restrict__ A, const __bf16* __restrict__ B,
    void* __restrict__ Cout, int K, int lda, int ldb, int ldc,
    const float* __restrict__ bias, const float* __restrict__ resid,
    long sA, long sB, long sC, long sR) {
  int z = blockIdx.z;
  A += (size_t)z * sA;
  B += (size_t)z * sB;
  __shared__ __bf16 lA[128 * 32];
  __shared__ __bf16 lB[128 * 32];
  int t = threadIdx.x, lane = t & 63, w = t >> 6;
  int row0 = blockIdx.x * 128, col0 = blockIdx.y * 128;
  int wr = w >> 1, wc = w & 1;
  f32x4 acc[4][4] = {};

  int sw = ((lane & 15) >> 1) & 3;
  int ca = ((lane >> 4) ^ sw) << 3;  // read-side swizzled chunk offset

  for (int k0 = 0; k0 < K; k0 += 32) {
    __syncthreads();
#pragma unroll
    for (int r = 0; r < 2; ++r) {
      int chunk = r * 256 + w * 64 + lane;
      int row = chunk >> 2;
      int csrc = ((chunk & 3) ^ ((row >> 1) & 3)) << 3;  // pre-swizzled source
      async_copy16(A + (size_t)(row0 + row) * lda + k0 + csrc,
                   lA + (r * 256 + w * 64) * 8);
    }
#pragma unroll
    for (int r = 0; r < 2; ++r) {
      int chunk = r * 256 + w * 64 + lane;
      int row = chunk >> 2;
      int csrc = ((chunk & 3) ^ ((row >> 1) & 3)) << 3;
      async_copy16(B + (size_t)(col0 + row) * ldb + k0 + csrc,
                   lB + (r * 256 + w * 64) * 8);
    }
    __syncthreads();
    bf16x8 af[4], bf[4];
#pragma unroll
    for (int i = 0; i < 4; ++i) {
      af[i] = *(const bf16x8*)(lA + (wr * 64 + i * 16 + (lane & 15)) * 32 + ca);
      bf[i] = *(const bf16x8*)(lB + (wc * 64 + i * 16 + (lane & 15)) * 32 + ca);
    }
#pragma unroll
    for (int i = 0; i < 4; ++i)
#pragma unroll
      for (int j = 0; j < 4; ++j)
        acc[i][j] = __builtin_amdgcn_mfma_f32_16x16x32_bf16(af[i], bf[j], acc[i][j], 0, 0, 0);
  }

  // epilogue: C/D layout col=lane&15, row=(lane>>4)*4+reg  [m89-verified]
  int rbase = row0 + wr * 64, cbase = col0 + wc * 64;
#pragma unroll
  for (int i = 0; i < 4; ++i) {
#pragma unroll
    for (int j = 0; j < 4; ++j) {
      int col = cbase + j * 16 + (lane & 15);
#pragma unroll
      for (int rg = 0; rg < 4; ++rg) {
        int row = rbase + i * 16 + (lane >> 4) * 4 + rg;
        float v = acc[i][j][rg];
        size_t idx = (size_t)z * sC + (size_t)row * ldc + col;
        if constexpr (EPI == 0) {
          ((__bf16*)Cout)[idx] = (__bf16)(v + bias[col]);
        } else if constexpr (EPI == 1) {
          ((__bf16*)Cout)[idx] = (__bf16)(v + bias[row]);
        } else if constexpr (EPI == 2) {
          ((float*)Cout)[idx] = v;
        } else if constexpr (EPI == 3) {
          ((float*)Cout)[idx] =
              v + bias[row] + resid[(size_t)z * sR + (size_t)row * ldc + col];
        } else {
          ((__bf16*)Cout)[idx] = (__bf16)v;
        }
      }
    }
  }
}

// ---------------------------------------------------------------- row softmax, in-place bf16 S -> bf16 P
__global__ __launch_bounds__(256) void softmax_rows_bf16(__bf16* __restrict__ S) {
  int row = blockIdx.x;
  __bf16* p = S + (size_t)row * 4096;
  int t = threadIdx.x, lane = t & 63, w = t >> 6;
  const float c1 = 0.04419417382415922f * 1.4426950408889634f;  // (1/sqrt(512))*log2(e)
  bf16x8 v0 = *(const bf16x8*)(p + t * 16);
  bf16x8 v1 = *(const bf16x8*)(p + t * 16 + 8);
  float f[16];
  float mx = -3.4e38f;
#pragma unroll
  for (int i = 0; i < 8; ++i) { f[i] = (float)v0[i]; mx = fmaxf(mx, f[i]); }
#pragma unroll
  for (int i = 0; i < 8; ++i) { f[8 + i] = (float)v1[i]; mx = fmaxf(mx, f[8 + i]); }
#pragma unroll
  for (int off = 32; off; off >>= 1) mx = fmaxf(mx, __shfl_xor(mx, off));
  __shared__ float rm[4], rsum[4];
  if (lane == 0) rm[w] = mx;
  __syncthreads();
  float m = fmaxf(fmaxf(rm[0], rm[1]), fmaxf(rm[2], rm[3]));
  float s = 0.f;
#pragma unroll
  for (int i = 0; i < 16; ++i) {
    f[i] = exp2f((f[i] - m) * c1);
    s += f[i];
  }
#pragma unroll
  for (int off = 32; off; off >>= 1) s += __shfl_xor(s, off);
  if (lane == 0) rsum[w] = s;
  __syncthreads();
  float inv = 1.0f / (rsum[0] + rsum[1] + rsum[2] + rsum[3]);
  bf16x8 o0, o1;
#pragma unroll
  for (int i = 0; i < 8; ++i) o0[i] = (__bf16)(f[i] * inv);
#pragma unroll
  for (int i = 0; i < 8; ++i) o1[i] = (__bf16)(f[8 + i] * inv);
  *(bf16x8*)(p + t * 16) = o0;
  *(bf16x8*)(p + t * 16 + 8) = o1;
}

// ---------------------------------------------------------------- launch
extern "C" void kernel_launch(void* const* d_in, const int* in_sizes, int n_in,
                              void* d_out, int out_size, void* d_ws, size_t ws_size,
                              hipStream_t stream) {
  const float* x = (const float*)d_in[0];
  const float* gamma = (const float*)d_in[1];
  const float* beta = (const float*)d_in[2];
  const float* wq = (const float*)d_in[3];
  const float* bq = (const float*)d_in[4];
  const float* wk = (const float*)d_in[5];
  const float* bk = (const float*)d_in[6];
  const float* wv = (const float*)d_in[7];
  const float* bv = (const float*)d_in[8];
  const float* wp = (const float*)d_in[9];
  const float* bp = (const float*)d_in[10];

  char* p = (char*)d_ws;
  auto alloc = [&](size_t bytes) {
    char* r = p;
    p += (bytes + 255) & ~(size_t)255;
    return r;
  };
  float* stats = (float*)alloc(256 * 2 * 4);
  __bf16* wqb = (__bf16*)alloc(512 * 512 * 2);
  __bf16* wkb = (__bf16*)alloc(512 * 512 * 2);
  __bf16* wvb = (__bf16*)alloc(512 * 512 * 2);
  __bf16* wpb = (__bf16*)alloc(512 * 512 * 2);
  __bf16* ho = (__bf16*)alloc((size_t)8 * 4096 * 512 * 2);  // h, later aliased as O
  __bf16* q = (__bf16*)alloc((size_t)8 * 4096 * 512 * 2);   // [B*N, C]
  __bf16* kb = (__bf16*)alloc((size_t)8 * 4096 * 512 * 2);  // [B*N, C]
  __bf16* vt = (__bf16*)alloc((size_t)8 * 512 * 4096 * 2);  // [B, C, N]

  // adaptive S chunking: bf16 [nb, 4096, 4096] = 32 MiB per batch
  const size_t SB = (size_t)4096 * 4096 * 2;
  size_t used = (size_t)(p - (char*)d_ws);
  int nb = (ws_size > used) ? (int)((ws_size - used) / SB) : 1;
  if (nb > 8) nb = 8;
  if (nb < 1) nb = 1;
  __bf16* s = (__bf16*)alloc(SB * nb);

  cvt_w<<<512, 256, 0, stream>>>(wq, wk, wv, wp, wqb, wkb, wvb, wpb);
  gn_stats<<<256, 256, 0, stream>>>(x, stats);
  gn_apply<<<dim3(16, 32, 8), 256, 0, stream>>>(x, gamma, beta, stats, ho);

  // Q = h Wq^T, K = h Wk^T  [32768,512]
  gemm_bt<0><<<dim3(256, 4, 1), 256, 0, stream>>>(ho, wqb, q, 512, 512, 512, 512,
                                                  bq, nullptr, 0, 0, 0, 0);
  gemm_bt<0><<<dim3(256, 4, 1), 256, 0, stream>>>(ho, wkb, kb, 512, 512, 512, 512,
                                                  bk, nullptr, 0, 0, 0, 0);
  // Vt[b] = Wv h[b]^T  [512,4096] per batch
  gemm_bt<1><<<dim3(4, 32, 8), 256, 0, stream>>>(wvb, ho, vt, 512, 512, 512, 4096,
                                                 bv, nullptr, 0, 2097152, 2097152, 0);

  // h is now dead -> O aliases it
  __bf16* o = ho;
  for (int b0 = 0; b0 < 8; b0 += nb) {
    int zb = (8 - b0 < nb) ? (8 - b0) : nb;
    // S = Q K^T (bf16 raw scores), batched over z
    gemm_bt<4><<<dim3(32, 32, zb), 256, 0, stream>>>(
        q + (size_t)b0 * 2097152, kb + (size_t)b0 * 2097152, (void*)s, 512, 512,
        512, 4096, nullptr, nullptr, 2097152, 2097152, 16777216, 0);
    softmax_rows_bf16<<<zb * 4096, 256, 0, stream>>>(s);
    // O = P V (P bf16 in-place over S), batched over z
    gemm_bt<4><<<dim3(32, 4, zb), 256, 0, stream>>>(
        s, vt + (size_t)b0 * 2097152, o + (size_t)b0 * 2097152, 4096, 4096, 4096,
        512, nullptr, nullptr, 16777216, 2097152, 2097152, 0);
  }
  // out = x + Wp O^T + bp  -> [B,C,N] f32
  gemm_bt<3><<<dim3(4, 32, 8), 256, 0, stream>>>(
      wpb, o, d_out, 512, 512, 512, 4096, bp, x, 0, 2097152, 2097152, 2097152);
}

// Round 4
// 810.379 us; speedup vs baseline: 1.6382x; 1.0641x over previous
//
#include <hip/hip_runtime.h>

// AttentionBlock: GN(32) -> q,k,v 1x1 -> softmax(qk^T/sqrt(C)) v -> proj + residual
// B=8, C=512, N=4096. All GEMMs bf16 MFMA GEMM_BT (m97 structure + T2 LDS swizzle).
// S stored bf16; attention core batched (nb from ws_size). PV uses BN=64 tiles
// (N=512 -> grid.y=8 -> 3 blocks/CU instead of 1.5; PV was grid-limited).

typedef __attribute__((ext_vector_type(8))) __bf16 bf16x8;
typedef __attribute__((ext_vector_type(4))) __bf16 bf16x4;
typedef __attribute__((ext_vector_type(4))) float f32x4;
typedef unsigned int u32;

#define DEVICE __device__ __forceinline__

DEVICE void async_copy16(const void* g, void* l) {
  __builtin_amdgcn_global_load_lds(
      (__attribute__((address_space(1))) u32*)(g),
      (__attribute__((address_space(3))) u32*)(l),
      16, 0, 0);
}

// ---------------------------------------------------------------- weights->bf16
__global__ __launch_bounds__(256) void cvt_w(
    const float* __restrict__ w0, const float* __restrict__ w1,
    const float* __restrict__ w2, const float* __restrict__ w3,
    __bf16* __restrict__ o0, __bf16* __restrict__ o1,
    __bf16* __restrict__ o2, __bf16* __restrict__ o3) {
  int idx = blockIdx.x * 256 + threadIdx.x;
  int off = idx * 8;
  int m = off >> 18;
  int r = off & 262143;
  const float* src = m == 0 ? w0 : m == 1 ? w1 : m == 2 ? w2 : w3;
  __bf16* dst = m == 0 ? o0 : m == 1 ? o1 : m == 2 ? o2 : o3;
  float4 a = *(const float4*)(src + r);
  float4 b = *(const float4*)(src + r + 4);
  bf16x8 v = {(__bf16)a.x, (__bf16)a.y, (__bf16)a.z, (__bf16)a.w,
              (__bf16)b.x, (__bf16)b.y, (__bf16)b.z, (__bf16)b.w};
  *(bf16x8*)(dst + r) = v;
}

// ---------------------------------------------------------------- groupnorm stats
__global__ __launch_bounds__(256) void gn_stats(const float* __restrict__ x,
                                                float* __restrict__ stats) {
  int bg = blockIdx.x;
  const float* p = x + (size_t)bg * 65536;
  int t = threadIdx.x, lane = t & 63, w = t >> 6;
  float s = 0.f, ss = 0.f;
  for (int i = t; i < 16384; i += 256) {
    float4 v = *(const float4*)(p + i * 4);
    s += v.x + v.y + v.z + v.w;
    ss += v.x * v.x + v.y * v.y + v.z * v.z + v.w * v.w;
  }
#pragma unroll
  for (int off = 32; off; off >>= 1) {
    s += __shfl_xor(s, off);
    ss += __shfl_xor(ss, off);
  }
  __shared__ float rs_[4], rss_[4];
  if (lane == 0) { rs_[w] = s; rss_[w] = ss; }
  __syncthreads();
  if (t == 0) {
    float S = rs_[0] + rs_[1] + rs_[2] + rs_[3];
    float SS = rss_[0] + rss_[1] + rss_[2] + rss_[3];
    float mean = S * (1.0f / 65536.0f);
    float var = SS * (1.0f / 65536.0f) - mean * mean;
    stats[bg * 2] = mean;
    stats[bg * 2 + 1] = rsqrtf(var + 1e-5f);
  }
}

// ---------------------------------------------------------------- groupnorm apply + transpose to [B,N,C] bf16
__global__ __launch_bounds__(256) void gn_apply(
    const float* __restrict__ x, const float* __restrict__ gamma,
    const float* __restrict__ beta, const float* __restrict__ stats,
    __bf16* __restrict__ h) {
  int b = blockIdx.z, g = blockIdx.y;
  int n = blockIdx.x * 256 + threadIdx.x;
  const float* px = x + ((size_t)b * 512 + g * 16) * 4096 + n;
  float mean = stats[(b * 32 + g) * 2];
  float rstd = stats[(b * 32 + g) * 2 + 1];
  bf16x8 lo, hi;
#pragma unroll
  for (int c = 0; c < 8; ++c) {
    float v = px[(size_t)c * 4096];
    lo[c] = (__bf16)((v - mean) * rstd * gamma[g * 16 + c] + beta[g * 16 + c]);
  }
#pragma unroll
  for (int c = 0; c < 8; ++c) {
    float v = px[(size_t)(c + 8) * 4096];
    hi[c] = (__bf16)((v - mean) * rstd * gamma[g * 16 + c + 8] + beta[g * 16 + c + 8]);
  }
  __bf16* dst = h + ((size_t)b * 4096 + n) * 512 + g * 16;
  *(bf16x8*)dst = lo;
  *(bf16x8*)(dst + 8) = hi;
}

// ---------------------------------------------------------------- GEMM_BT
// C[m,n] = sum_k A[m,k]*B[n,k]  (A:[M,K] lda, B:[N,K] ldb, both bf16)
// 128xBN tile (BN=128 or 64), BK=32, 4 waves (2x2), wave tile 64x(BN/2).
// T2 LDS swizzle: 16B chunk c of row r at slot c^((r>>1)&3), both sides (rule #21).
// EPI: 0 bf16+colbias | 1 bf16+rowbias | 2 f32 raw | 3 f32+rowbias+resid | 4 bf16
template <int EPI, int BN = 128>
__global__ __launch_bounds__(256) void gemm_bt(
    const __bf16* __restrict__ A, const __bf16* __restrict__ B,
    void* __restrict__ Cout, int K, int lda, int ldb, int ldc,
    const float* __restrict__ bias, const float* __restrict__ resid,
    long sA, long sB, long sC, long sR) {
  constexpr int NF = BN / 32;  // N-frags per wave (2 wave-cols of NF*16)
  int z = blockIdx.z;
  A += (size_t)z * sA;
  B += (size_t)z * sB;
  __shared__ __bf16 lA[128 * 32];
  __shared__ __bf16 lB[BN * 32];
  int t = threadIdx.x, lane = t & 63, w = t >> 6;
  int row0 = blockIdx.x * 128, col0 = blockIdx.y * BN;
  int wr = w >> 1, wc = w & 1;
  f32x4 acc[4][NF] = {};

  int sw = ((lane & 15) >> 1) & 3;
  int ca = ((lane >> 4) ^ sw) << 3;  // read-side swizzled chunk offset

  for (int k0 = 0; k0 < K; k0 += 32) {
    __syncthreads();
#pragma unroll
    for (int r = 0; r < 2; ++r) {
      int chunk = r * 256 + w * 64 + lane;
      int row = chunk >> 2;
      int csrc = ((chunk & 3) ^ ((row >> 1) & 3)) << 3;  // pre-swizzled source
      async_copy16(A + (size_t)(row0 + row) * lda + k0 + csrc,
                   lA + (r * 256 + w * 64) * 8);
    }
#pragma unroll
    for (int r = 0; r < BN / 64; ++r) {
      int chunk = r * 256 + w * 64 + lane;
      int row = chunk >> 2;
      int csrc = ((chunk & 3) ^ ((row >> 1) & 3)) << 3;
      async_copy16(B + (size_t)(col0 + row) * ldb + k0 + csrc,
                   lB + (r * 256 + w * 64) * 8);
    }
    __syncthreads();
    bf16x8 af[4], bf[NF];
#pragma unroll
    for (int i = 0; i < 4; ++i)
      af[i] = *(const bf16x8*)(lA + (wr * 64 + i * 16 + (lane & 15)) * 32 + ca);
#pragma unroll
    for (int j = 0; j < NF; ++j)
      bf[j] = *(const bf16x8*)(lB + (wc * (NF * 16) + j * 16 + (lane & 15)) * 32 + ca);
#pragma unroll
    for (int i = 0; i < 4; ++i)
#pragma unroll
      for (int j = 0; j < NF; ++j)
        acc[i][j] = __builtin_amdgcn_mfma_f32_16x16x32_bf16(af[i], bf[j], acc[i][j], 0, 0, 0);
  }

  // epilogue: C/D layout col=lane&15, row=(lane>>4)*4+reg  [m89-verified]
  int rbase = row0 + wr * 64, cbase = col0 + wc * (NF * 16);
#pragma unroll
  for (int i = 0; i < 4; ++i) {
#pragma unroll
    for (int j = 0; j < NF; ++j) {
      int col = cbase + j * 16 + (lane & 15);
#pragma unroll
      for (int rg = 0; rg < 4; ++rg) {
        int row = rbase + i * 16 + (lane >> 4) * 4 + rg;
        float v = acc[i][j][rg];
        size_t idx = (size_t)z * sC + (size_t)row * ldc + col;
        if constexpr (EPI == 0) {
          ((__bf16*)Cout)[idx] = (__bf16)(v + bias[col]);
        } else if constexpr (EPI == 1) {
          ((__bf16*)Cout)[idx] = (__bf16)(v + bias[row]);
        } else if constexpr (EPI == 2) {
          ((float*)Cout)[idx] = v;
        } else if constexpr (EPI == 3) {
          ((float*)Cout)[idx] =
              v + bias[row] + resid[(size_t)z * sR + (size_t)row * ldc + col];
        } else {
          ((__bf16*)Cout)[idx] = (__bf16)v;
        }
      }
    }
  }
}

// ---------------------------------------------------------------- row softmax, in-place bf16 S -> bf16 P
__global__ __launch_bounds__(256) void softmax_rows_bf16(__bf16* __restrict__ S) {
  int row = blockIdx.x;
  __bf16* p = S + (size_t)row * 4096;
  int t = threadIdx.x, lane = t & 63, w = t >> 6;
  const float c1 = 0.04419417382415922f * 1.4426950408889634f;  // (1/sqrt(512))*log2(e)
  bf16x8 v0 = *(const bf16x8*)(p + t * 16);
  bf16x8 v1 = *(const bf16x8*)(p + t * 16 + 8);
  float f[16];
  float mx = -3.4e38f;
#pragma unroll
  for (int i = 0; i < 8; ++i) { f[i] = (float)v0[i]; mx = fmaxf(mx, f[i]); }
#pragma unroll
  for (int i = 0; i < 8; ++i) { f[8 + i] = (float)v1[i]; mx = fmaxf(mx, f[8 + i]); }
#pragma unroll
  for (int off = 32; off; off >>= 1) mx = fmaxf(mx, __shfl_xor(mx, off));
  __shared__ float rm[4], rsum[4];
  if (lane == 0) rm[w] = mx;
  __syncthreads();
  float m = fmaxf(fmaxf(rm[0], rm[1]), fmaxf(rm[2], rm[3]));
  float s = 0.f;
#pragma unroll
  for (int i = 0; i < 16; ++i) {
    f[i] = exp2f((f[i] - m) * c1);
    s += f[i];
  }
#pragma unroll
  for (int off = 32; off; off >>= 1) s += __shfl_xor(s, off);
  if (lane == 0) rsum[w] = s;
  __syncthreads();
  float inv = 1.0f / (rsum[0] + rsum[1] + rsum[2] + rsum[3]);
  bf16x8 o0, o1;
#pragma unroll
  for (int i = 0; i < 8; ++i) o0[i] = (__bf16)(f[i] * inv);
#pragma unroll
  for (int i = 0; i < 8; ++i) o1[i] = (__bf16)(f[8 + i] * inv);
  *(bf16x8*)(p + t * 16) = o0;
  *(bf16x8*)(p + t * 16 + 8) = o1;
}

// ---------------------------------------------------------------- launch
extern "C" void kernel_launch(void* const* d_in, const int* in_sizes, int n_in,
                              void* d_out, int out_size, void* d_ws, size_t ws_size,
                              hipStream_t stream) {
  const float* x = (const float*)d_in[0];
  const float* gamma = (const float*)d_in[1];
  const float* beta = (const float*)d_in[2];
  const float* wq = (const float*)d_in[3];
  const float* bq = (const float*)d_in[4];
  const float* wk = (const float*)d_in[5];
  const float* bk = (const float*)d_in[6];
  const float* wv = (const float*)d_in[7];
  const float* bv = (const float*)d_in[8];
  const float* wp = (const float*)d_in[9];
  const float* bp = (const float*)d_in[10];

  char* p = (char*)d_ws;
  auto alloc = [&](size_t bytes) {
    char* r = p;
    p += (bytes + 255) & ~(size_t)255;
    return r;
  };
  float* stats = (float*)alloc(256 * 2 * 4);
  __bf16* wqb = (__bf16*)alloc(512 * 512 * 2);
  __bf16* wkb = (__bf16*)alloc(512 * 512 * 2);
  __bf16* wvb = (__bf16*)alloc(512 * 512 * 2);
  __bf16* wpb = (__bf16*)alloc(512 * 512 * 2);
  __bf16* ho = (__bf16*)alloc((size_t)8 * 4096 * 512 * 2);  // h, later aliased as O
  __bf16* q = (__bf16*)alloc((size_t)8 * 4096 * 512 * 2);   // [B*N, C]
  __bf16* kb = (__bf16*)alloc((size_t)8 * 4096 * 512 * 2);  // [B*N, C]
  __bf16* vt = (__bf16*)alloc((size_t)8 * 512 * 4096 * 2);  // [B, C, N]

  // adaptive S chunking: bf16 [nb, 4096, 4096] = 32 MiB per batch
  const size_t SB = (size_t)4096 * 4096 * 2;
  size_t used = (size_t)(p - (char*)d_ws);
  int nb = (ws_size > used) ? (int)((ws_size - used) / SB) : 1;
  if (nb > 8) nb = 8;
  if (nb < 1) nb = 1;
  __bf16* s = (__bf16*)alloc(SB * nb);

  cvt_w<<<512, 256, 0, stream>>>(wq, wk, wv, wp, wqb, wkb, wvb, wpb);
  gn_stats<<<256, 256, 0, stream>>>(x, stats);
  gn_apply<<<dim3(16, 32, 8), 256, 0, stream>>>(x, gamma, beta, stats, ho);

  // Q = h Wq^T, K = h Wk^T  [32768,512]
  gemm_bt<0><<<dim3(256, 4, 1), 256, 0, stream>>>(ho, wqb, q, 512, 512, 512, 512,
                                                  bq, nullptr, 0, 0, 0, 0);
  gemm_bt<0><<<dim3(256, 4, 1), 256, 0, stream>>>(ho, wkb, kb, 512, 512, 512, 512,
                                                  bk, nullptr, 0, 0, 0, 0);
  // Vt[b] = Wv h[b]^T  [512,4096] per batch
  gemm_bt<1><<<dim3(4, 32, 8), 256, 0, stream>>>(wvb, ho, vt, 512, 512, 512, 4096,
                                                 bv, nullptr, 0, 2097152, 2097152, 0);

  // h is now dead -> O aliases it
  __bf16* o = ho;
  for (int b0 = 0; b0 < 8; b0 += nb) {
    int zb = (8 - b0 < nb) ? (8 - b0) : nb;
    // S = Q K^T (bf16 raw scores), batched over z
    gemm_bt<4><<<dim3(32, 32, zb), 256, 0, stream>>>(
        q + (size_t)b0 * 2097152, kb + (size_t)b0 * 2097152, (void*)s, 512, 512,
        512, 4096, nullptr, nullptr, 2097152, 2097152, 16777216, 0);
    softmax_rows_bf16<<<zb * 4096, 256, 0, stream>>>(s);
    // O = P V (P bf16 in-place over S), BN=64 tiles -> grid.y=8, batched over z
    gemm_bt<4, 64><<<dim3(32, 8, zb), 256, 0, stream>>>(
        s, vt + (size_t)b0 * 2097152, o + (size_t)b0 * 2097152, 4096, 4096, 4096,
        512, nullptr, nullptr, 16777216, 2097152, 2097152, 0);
  }
  // out = x + Wp O^T + bp  -> [B,C,N] f32
  gemm_bt<3><<<dim3(4, 32, 8), 256, 0, stream>>>(
      wpb, o, d_out, 512, 512, 512, 4096, bp, x, 0, 2097152, 2097152, 2097152);
}

// Round 5
// 639.768 us; speedup vs baseline: 2.0751x; 1.2667x over previous
//
#include <hip/hip_runtime.h>

// AttentionBlock: GN(32) -> q,k,v 1x1 -> softmax(qk^T/sqrt(C)) v -> proj + residual
// B=8, C=512, N=4096.
// QK^T and PV run on gemm256: 256x256 8-phase counted-vmcnt template (T2+T3+T4+T5).
// PV is K-split x4 (N=512) with bf16 partials + reduce. Projections stay on the
// 128-tile 2-barrier gemm_bt (small). nb=2 batches per attention chunk.

typedef __attribute__((ext_vector_type(8))) __bf16 bf16x8;
typedef __attribute__((ext_vector_type(4))) __bf16 bf16x4;
typedef __attribute__((ext_vector_type(4))) float f32x4;
typedef unsigned int u32;

#define DEVICE __device__ __forceinline__

DEVICE void async_copy16(const void* g, void* l) {
  __builtin_amdgcn_global_load_lds(
      (__attribute__((address_space(1))) u32*)(g),
      (__attribute__((address_space(3))) u32*)(l),
      16, 0, 0);
}

// ---------------------------------------------------------------- weights->bf16
__global__ __launch_bounds__(256) void cvt_w(
    const float* __restrict__ w0, const float* __restrict__ w1,
    const float* __restrict__ w2, const float* __restrict__ w3,
    __bf16* __restrict__ o0, __bf16* __restrict__ o1,
    __bf16* __restrict__ o2, __bf16* __restrict__ o3) {
  int idx = blockIdx.x * 256 + threadIdx.x;
  int off = idx * 8;
  int m = off >> 18;
  int r = off & 262143;
  const float* src = m == 0 ? w0 : m == 1 ? w1 : m == 2 ? w2 : w3;
  __bf16* dst = m == 0 ? o0 : m == 1 ? o1 : m == 2 ? o2 : o3;
  float4 a = *(const float4*)(src + r);
  float4 b = *(const float4*)(src + r + 4);
  bf16x8 v = {(__bf16)a.x, (__bf16)a.y, (__bf16)a.z, (__bf16)a.w,
              (__bf16)b.x, (__bf16)b.y, (__bf16)b.z, (__bf16)b.w};
  *(bf16x8*)(dst + r) = v;
}

// ---------------------------------------------------------------- groupnorm stats
__global__ __launch_bounds__(256) void gn_stats(const float* __restrict__ x,
                                                float* __restrict__ stats) {
  int bg = blockIdx.x;
  const float* p = x + (size_t)bg * 65536;
  int t = threadIdx.x, lane = t & 63, w = t >> 6;
  float s = 0.f, ss = 0.f;
  for (int i = t; i < 16384; i += 256) {
    float4 v = *(const float4*)(p + i * 4);
    s += v.x + v.y + v.z + v.w;
    ss += v.x * v.x + v.y * v.y + v.z * v.z + v.w * v.w;
  }
#pragma unroll
  for (int off = 32; off; off >>= 1) {
    s += __shfl_xor(s, off);
    ss += __shfl_xor(ss, off);
  }
  __shared__ float rs_[4], rss_[4];
  if (lane == 0) { rs_[w] = s; rss_[w] = ss; }
  __syncthreads();
  if (t == 0) {
    float S = rs_[0] + rs_[1] + rs_[2] + rs_[3];
    float SS = rss_[0] + rss_[1] + rss_[2] + rss_[3];
    float mean = S * (1.0f / 65536.0f);
    float var = SS * (1.0f / 65536.0f) - mean * mean;
    stats[bg * 2] = mean;
    stats[bg * 2 + 1] = rsqrtf(var + 1e-5f);
  }
}

// ---------------------------------------------------------------- groupnorm apply + transpose to [B,N,C] bf16
__global__ __launch_bounds__(256) void gn_apply(
    const float* __restrict__ x, const float* __restrict__ gamma,
    const float* __restrict__ beta, const float* __restrict__ stats,
    __bf16* __restrict__ h) {
  int b = blockIdx.z, g = blockIdx.y;
  int n = blockIdx.x * 256 + threadIdx.x;
  const float* px = x + ((size_t)b * 512 + g * 16) * 4096 + n;
  float mean = stats[(b * 32 + g) * 2];
  float rstd = stats[(b * 32 + g) * 2 + 1];
  bf16x8 lo, hi;
#pragma unroll
  for (int c = 0; c < 8; ++c) {
    float v = px[(size_t)c * 4096];
    lo[c] = (__bf16)((v - mean) * rstd * gamma[g * 16 + c] + beta[g * 16 + c]);
  }
#pragma unroll
  for (int c = 0; c < 8; ++c) {
    float v = px[(size_t)(c + 8) * 4096];
    hi[c] = (__bf16)((v - mean) * rstd * gamma[g * 16 + c + 8] + beta[g * 16 + c + 8]);
  }
  __bf16* dst = h + ((size_t)b * 4096 + n) * 512 + g * 16;
  *(bf16x8*)dst = lo;
  *(bf16x8*)(dst + 8) = hi;
}

// ---------------------------------------------------------------- gemm_bt (128-tile, 2-barrier) for projections
// C[m,n] = sum_k A[m,k]*B[n,k]. EPI: 0 bf16+colbias | 1 bf16+rowbias | 3 f32+rowbias+resid
template <int EPI>
__global__ __launch_bounds__(256) void gemm_bt(
    const __bf16* __restrict__ A, const __bf16* __restrict__ B,
    void* __restrict__ Cout, int K, int lda, int ldb, int ldc,
    const float* __restrict__ bias, const float* __restrict__ resid,
    long sA, long sB, long sC, long sR) {
  int z = blockIdx.z;
  A += (size_t)z * sA;
  B += (size_t)z * sB;
  __shared__ __bf16 lA[128 * 32];
  __shared__ __bf16 lB[128 * 32];
  int t = threadIdx.x, lane = t & 63, w = t >> 6;
  int row0 = blockIdx.x * 128, col0 = blockIdx.y * 128;
  int wr = w >> 1, wc = w & 1;
  f32x4 acc[4][4] = {};

  int sw = ((lane & 15) >> 1) & 3;
  int ca = ((lane >> 4) ^ sw) << 3;

  for (int k0 = 0; k0 < K; k0 += 32) {
    __syncthreads();
#pragma unroll
    for (int r = 0; r < 2; ++r) {
      int chunk = r * 256 + w * 64 + lane;
      int row = chunk >> 2;
      int csrc = ((chunk & 3) ^ ((row >> 1) & 3)) << 3;
      async_copy16(A + (size_t)(row0 + row) * lda + k0 + csrc,
                   lA + (r * 256 + w * 64) * 8);
    }
#pragma unroll
    for (int r = 0; r < 2; ++r) {
      int chunk = r * 256 + w * 64 + lane;
      int row = chunk >> 2;
      int csrc = ((chunk & 3) ^ ((row >> 1) & 3)) << 3;
      async_copy16(B + (size_t)(col0 + row) * ldb + k0 + csrc,
                   lB + (r * 256 + w * 64) * 8);
    }
    __syncthreads();
    bf16x8 af[4], bf[4];
#pragma unroll
    for (int i = 0; i < 4; ++i) {
      af[i] = *(const bf16x8*)(lA + (wr * 64 + i * 16 + (lane & 15)) * 32 + ca);
      bf[i] = *(const bf16x8*)(lB + (wc * 64 + i * 16 + (lane & 15)) * 32 + ca);
    }
#pragma unroll
    for (int i = 0; i < 4; ++i)
#pragma unroll
      for (int j = 0; j < 4; ++j)
        acc[i][j] = __builtin_amdgcn_mfma_f32_16x16x32_bf16(af[i], bf[j], acc[i][j], 0, 0, 0);
  }

  int rbase = row0 + wr * 64, cbase = col0 + wc * 64;
#pragma unroll
  for (int i = 0; i < 4; ++i) {
#pragma unroll
    for (int j = 0; j < 4; ++j) {
      int col = cbase + j * 16 + (lane & 15);
#pragma unroll
      for (int rg = 0; rg < 4; ++rg) {
        int row = rbase + i * 16 + (lane >> 4) * 4 + rg;
        float v = acc[i][j][rg];
        size_t idx = (size_t)z * sC + (size_t)row * ldc + col;
        if constexpr (EPI == 0) {
          ((__bf16*)Cout)[idx] = (__bf16)(v + bias[col]);
        } else if constexpr (EPI == 1) {
          ((__bf16*)Cout)[idx] = (__bf16)(v + bias[row]);
        } else {
          ((float*)Cout)[idx] =
              v + bias[row] + resid[(size_t)z * sR + (size_t)row * ldc + col];
        }
      }
    }
  }
}

// ---------------------------------------------------------------- gemm256: 256x256 8-phase template
// C[m,n] = sum_k A[m,k]*B[n,k], bf16 out. 512 thr = 8 waves (2M x 4N), BK=64,
// LDS 128 KiB dbuf. Counted vmcnt(4) at phases 3/7 (T4); setprio around MFMA (T5);
// chunk^=(row&7) swizzle both-sides (T2, rule #21); bijective XCD swizzle (T1).
// zz = flattened (z,ks): A += z*sA + ks*sKA, B += z*sB + ks*sKB, C += zz*sC.

#define G256_PHASE(BUF, QR, QC, RDA, RDB, STAGE_STMT, TAIL_STMT)               \
  do {                                                                         \
    if (RDA) {                                                                 \
      _Pragma("unroll") for (int fr = 0; fr < 4; ++fr) {                       \
        a[fr][0] = ldA(BUF, (QR)*4 + fr, 0);                                   \
        a[fr][1] = ldA(BUF, (QR)*4 + fr, 1);                                   \
      }                                                                        \
    }                                                                          \
    if (RDB) {                                                                 \
      _Pragma("unroll") for (int fc = 0; fc < 2; ++fc) {                       \
        b[(QC)*2 + fc][0] = ldB(BUF, (QC)*2 + fc, 0);                          \
        b[(QC)*2 + fc][1] = ldB(BUF, (QC)*2 + fc, 1);                          \
      }                                                                        \
    }                                                                          \
    STAGE_STMT;                                                                \
    __builtin_amdgcn_s_barrier();                                              \
    asm volatile("s_waitcnt lgkmcnt(0)" ::: "memory");                         \
    __builtin_amdgcn_sched_barrier(0);                                         \
    __builtin_amdgcn_s_setprio(1);                                             \
    _Pragma("unroll") for (int fr = 0; fr < 4; ++fr)                           \
      _Pragma("unroll") for (int fc = 0; fc < 2; ++fc) {                       \
        acc[(QR)*4 + fr][(QC)*2 + fc] =                                        \
            __builtin_amdgcn_mfma_f32_16x16x32_bf16(                           \
                a[fr][0], b[(QC)*2 + fc][0], acc[(QR)*4 + fr][(QC)*2 + fc],    \
                0, 0, 0);                                                      \
        acc[(QR)*4 + fr][(QC)*2 + fc] =                                        \
            __builtin_amdgcn_mfma_f32_16x16x32_bf16(                           \
                a[fr][1], b[(QC)*2 + fc][1], acc[(QR)*4 + fr][(QC)*2 + fc],    \
                0, 0, 0);                                                      \
      }                                                                        \
    __builtin_amdgcn_s_setprio(0);                                             \
    TAIL_STMT;                                                                 \
    __builtin_amdgcn_sched_barrier(0);                                         \
    __builtin_amdgcn_s_barrier();                                              \
  } while (0)

#define G256_ITER(T0, T1, LAST)                                                \
  G256_PHASE(0, 0, 0, 1, 1, stage(1, 0, 0, (T1)), ((void)0));                  \
  G256_PHASE(0, 0, 1, 0, 1, stage(1, 0, 1, (T1)), ((void)0));                  \
  G256_PHASE(0, 1, 0, 1, 0,                                                    \
             if (!(LAST)) stage(0, 1, 0, (T0) + 2), ((void)0));                \
  G256_PHASE(0, 1, 1, 0, 0,                                                    \
             if (!(LAST)) stage(0, 1, 1, (T0) + 2),                            \
             if (LAST) {                                                       \
               asm volatile("s_waitcnt vmcnt(0)" ::: "memory");                \
             } else {                                                          \
               asm volatile("s_waitcnt vmcnt(4)" ::: "memory");                \
             });                                                               \
  G256_PHASE(1, 0, 0, 1, 1,                                                    \
             if (!(LAST)) stage(0, 0, 0, (T0) + 2), ((void)0));                \
  G256_PHASE(1, 0, 1, 0, 1,                                                    \
             if (!(LAST)) stage(0, 0, 1, (T0) + 2), ((void)0));                \
  G256_PHASE(1, 1, 0, 1, 0,                                                    \
             if (!(LAST)) stage(1, 1, 0, (T1) + 2), ((void)0));                \
  G256_PHASE(1, 1, 1, 0, 0,                                                    \
             if (!(LAST)) stage(1, 1, 1, (T1) + 2),                            \
             if (!(LAST)) {                                                    \
               asm volatile("s_waitcnt vmcnt(4)" ::: "memory");                \
             })

__global__ __launch_bounds__(512, 2) void gemm256(
    const __bf16* __restrict__ A, const __bf16* __restrict__ B,
    __bf16* __restrict__ Cout, int lda, int ldb, int ldc, int nIter, int nTM,
    int nTN, int KS, long sA, long sKA, long sB, long sKB, long sC) {
  // [buf][mat][half][128 rows][64 k] bf16 = 128 KiB
  __shared__ __bf16 lds_raw[2][2][2][128][64];

  int nwg = gridDim.x, bid = blockIdx.x;
  int qq = nwg >> 3, rr = nwg & 7;
  int xcd = bid & 7, ii = bid >> 3;
  int swz = (xcd < rr ? xcd * (qq + 1) : rr * (qq + 1) + (xcd - rr) * qq) + ii;
  int tn = swz % nTN;
  int tm = (swz / nTN) % nTM;
  int zz = swz / (nTN * nTM);
  int z = zz / KS, ks = zz % KS;
  A += (size_t)z * sA + (size_t)ks * sKA;
  B += (size_t)z * sB + (size_t)ks * sKB;
  Cout += (size_t)zz * sC;
  int row0 = tm * 256, col0 = tn * 256;

  int tid = threadIdx.x;
  int wid = tid >> 6, lane = tid & 63;
  int wr = wid >> 2, wc = wid & 3;  // wave tile: rows wr*128, cols wc*64
  int l15 = lane & 15, l4 = lane >> 4;

  // stage one 16KB half-tile (2 gload_lds / thread); linear LDS dest,
  // pre-swizzled global source (chunk ^ (row&7))
  auto stage = [&](int buf, int mat, int half, int kt) {
    const __bf16* src = mat ? B : A;
    int ld = mat ? ldb : lda;
    int rbase = (mat ? col0 : row0) + half * 128;
    char* ldsbase =
        (char*)lds_raw + (((buf * 2 + mat) * 2 + half) * 16384);
#pragma unroll
    for (int L = 0; L < 2; ++L) {
      int ci = L * 512 + tid;
      int r = ci >> 3, cslot = ci & 7;
      int csrc = cslot ^ (r & 7);
      async_copy16(src + (size_t)(rbase + r) * ld + kt * 64 + csrc * 8,
                   ldsbase + (L * 512 + wid * 64) * 16);
    }
  };
  auto ldA = [&](int buf, int fr, int kh) -> bf16x8 {
    int row = fr * 16 + l15;
    int g = kh * 4 + l4;
    char* base = (char*)lds_raw + (((buf * 2 + 0) * 2 + wr) * 16384);
    return *(const bf16x8*)(base + row * 128 + ((g ^ (row & 7)) * 16));
  };
  auto ldB = [&](int buf, int fc, int kh) -> bf16x8 {
    int row = (wc & 1) * 64 + fc * 16 + l15;
    int g = kh * 4 + l4;
    char* base = (char*)lds_raw + (((buf * 2 + 1) * 2 + (wc >> 1)) * 16384);
    return *(const bf16x8*)(base + row * 128 + ((g ^ (row & 7)) * 16));
  };

  f32x4 acc[8][4] = {};
  bf16x8 a[4][2], b[4][2];

  // prologue: buf0 {B,A} of ktile 0, buf1 {B} of ktile 1; drain buf0 only
  stage(0, 1, 0, 0);
  stage(0, 1, 1, 0);
  stage(0, 0, 0, 0);
  stage(0, 0, 1, 0);
  stage(1, 1, 0, 1);
  stage(1, 1, 1, 1);
  asm volatile("s_waitcnt vmcnt(4)" ::: "memory");
  __builtin_amdgcn_sched_barrier(0);
  __builtin_amdgcn_s_barrier();

  int it = 0;
  for (; it < nIter - 1; ++it) {
    G256_ITER(2 * it, 2 * it + 1, 0);
  }
  G256_ITER(2 * it, 2 * it + 1, 1);

  // epilogue: C/D layout col=lane&15, row=(lane>>4)*4+rg
  int rb = row0 + wr * 128, cb = col0 + wc * 64;
#pragma unroll
  for (int fr = 0; fr < 8; ++fr) {
#pragma unroll
    for (int fc = 0; fc < 4; ++fc) {
      int col = cb + fc * 16 + l15;
#pragma unroll
      for (int rg = 0; rg < 4; ++rg) {
        int row = rb + fr * 16 + l4 * 4 + rg;
        Cout[(size_t)row * ldc + col] = (__bf16)acc[fr][fc][rg];
      }
    }
  }
}

// ---------------------------------------------------------------- row softmax, in-place bf16 S -> bf16 P
__global__ __launch_bounds__(256) void softmax_rows_bf16(__bf16* __restrict__ S) {
  int row = blockIdx.x;
  __bf16* p = S + (size_t)row * 4096;
  int t = threadIdx.x, lane = t & 63, w = t >> 6;
  const float c1 = 0.04419417382415922f * 1.4426950408889634f;
  bf16x8 v0 = *(const bf16x8*)(p + t * 16);
  bf16x8 v1 = *(const bf16x8*)(p + t * 16 + 8);
  float f[16];
  float mx = -3.4e38f;
#pragma unroll
  for (int i = 0; i < 8; ++i) { f[i] = (float)v0[i]; mx = fmaxf(mx, f[i]); }
#pragma unroll
  for (int i = 0; i < 8; ++i) { f[8 + i] = (float)v1[i]; mx = fmaxf(mx, f[8 + i]); }
#pragma unroll
  for (int off = 32; off; off >>= 1) mx = fmaxf(mx, __shfl_xor(mx, off));
  __shared__ float rm[4], rsum[4];
  if (lane == 0) rm[w] = mx;
  __syncthreads();
  float m = fmaxf(fmaxf(rm[0], rm[1]), fmaxf(rm[2], rm[3]));
  float s = 0.f;
#pragma unroll
  for (int i = 0; i < 16; ++i) {
    f[i] = exp2f((f[i] - m) * c1);
    s += f[i];
  }
#pragma unroll
  for (int off = 32; off; off >>= 1) s += __shfl_xor(s, off);
  if (lane == 0) rsum[w] = s;
  __syncthreads();
  float inv = 1.0f / (rsum[0] + rsum[1] + rsum[2] + rsum[3]);
  bf16x8 o0, o1;
#pragma unroll
  for (int i = 0; i < 8; ++i) o0[i] = (__bf16)(f[i] * inv);
#pragma unroll
  for (int i = 0; i < 8; ++i) o1[i] = (__bf16)(f[8 + i] * inv);
  *(bf16x8*)(p + t * 16) = o0;
  *(bf16x8*)(p + t * 16 + 8) = o1;
}

// ---------------------------------------------------------------- sum 4 K-split partials -> O
__global__ __launch_bounds__(256) void reduce4(const __bf16* __restrict__ part,
                                               __bf16* __restrict__ out) {
  int z = blockIdx.y;
  size_t e = ((size_t)blockIdx.x * 256 + threadIdx.x) * 8;
  const __bf16* p = part + (size_t)z * 4 * 2097152 + e;
  bf16x8 v0 = *(const bf16x8*)(p);
  bf16x8 v1 = *(const bf16x8*)(p + 2097152);
  bf16x8 v2 = *(const bf16x8*)(p + 2 * 2097152);
  bf16x8 v3 = *(const bf16x8*)(p + 3 * 2097152);
  bf16x8 o;
#pragma unroll
  for (int j = 0; j < 8; ++j)
    o[j] = (__bf16)((float)v0[j] + (float)v1[j] + (float)v2[j] + (float)v3[j]);
  *(bf16x8*)(out + (size_t)z * 2097152 + e) = o;
}

// ---------------------------------------------------------------- launch
extern "C" void kernel_launch(void* const* d_in, const int* in_sizes, int n_in,
                              void* d_out, int out_size, void* d_ws, size_t ws_size,
                              hipStream_t stream) {
  const float* x = (const float*)d_in[0];
  const float* gamma = (const float*)d_in[1];
  const float* beta = (const float*)d_in[2];
  const float* wq = (const float*)d_in[3];
  const float* bq = (const float*)d_in[4];
  const float* wk = (const float*)d_in[5];
  const float* bk = (const float*)d_in[6];
  const float* wv = (const float*)d_in[7];
  const float* bv = (const float*)d_in[8];
  const float* wp = (const float*)d_in[9];
  const float* bp = (const float*)d_in[10];

  char* p = (char*)d_ws;
  auto alloc = [&](size_t bytes) {
    char* r = p;
    p += (bytes + 255) & ~(size_t)255;
    return r;
  };
  float* stats = (float*)alloc(256 * 2 * 4);
  __bf16* wqb = (__bf16*)alloc(512 * 512 * 2);
  __bf16* wkb = (__bf16*)alloc(512 * 512 * 2);
  __bf16* wvb = (__bf16*)alloc(512 * 512 * 2);
  __bf16* wpb = (__bf16*)alloc(512 * 512 * 2);
  __bf16* ho = (__bf16*)alloc((size_t)8 * 4096 * 512 * 2);  // h, later aliased as O
  __bf16* q = (__bf16*)alloc((size_t)8 * 4096 * 512 * 2);   // [B*N, C]
  __bf16* kb = (__bf16*)alloc((size_t)8 * 4096 * 512 * 2);  // [B*N, C]
  __bf16* vt = (__bf16*)alloc((size_t)8 * 512 * 4096 * 2);  // [B, C, N]

  // per-chunk: S bf16 [nb,4096,4096] (32 MiB/b) + PV partials [nb,4,4096,512] (16 MiB/b)
  const size_t SB = (size_t)4096 * 4096 * 2;
  const size_t PB = (size_t)4 * 4096 * 512 * 2;
  size_t used = (size_t)(p - (char*)d_ws);
  size_t freeb = (ws_size > used) ? ws_size - used : 0;
  int nb = (int)(freeb / (SB + PB));
  if (nb > 8) nb = 8;
  if (nb < 1) nb = 1;
  __bf16* s = (__bf16*)alloc(SB * nb);
  __bf16* pvp = (__bf16*)alloc(PB * nb);

  cvt_w<<<512, 256, 0, stream>>>(wq, wk, wv, wp, wqb, wkb, wvb, wpb);
  gn_stats<<<256, 256, 0, stream>>>(x, stats);
  gn_apply<<<dim3(16, 32, 8), 256, 0, stream>>>(x, gamma, beta, stats, ho);

  // Q = h Wq^T, K = h Wk^T  [32768,512]
  gemm_bt<0><<<dim3(256, 4, 1), 256, 0, stream>>>(ho, wqb, q, 512, 512, 512, 512,
                                                  bq, nullptr, 0, 0, 0, 0);
  gemm_bt<0><<<dim3(256, 4, 1), 256, 0, stream>>>(ho, wkb, kb, 512, 512, 512, 512,
                                                  bk, nullptr, 0, 0, 0, 0);
  // Vt[b] = Wv h[b]^T  [512,4096] per batch
  gemm_bt<1><<<dim3(4, 32, 8), 256, 0, stream>>>(wvb, ho, vt, 512, 512, 512, 4096,
                                                 bv, nullptr, 0, 2097152, 2097152, 0);

  __bf16* o = ho;  // h dead -> O aliases it
  for (int b0 = 0; b0 < 8; b0 += nb) {
    int zb = (8 - b0 < nb) ? (8 - b0) : nb;
    // S = Q K^T (bf16 raw scores): M=N=4096, K=512 (nIter=4), grid zb*256
    gemm256<<<dim3(zb * 256), 512, 0, stream>>>(
        q + (size_t)b0 * 2097152, kb + (size_t)b0 * 2097152, s, 512, 512, 4096,
        4, 16, 16, 1, 2097152, 0, 2097152, 0, 16777216);
    softmax_rows_bf16<<<zb * 4096, 256, 0, stream>>>(s);
    // partial O = P V, K-split x4: M=4096, N=512, Ksub=1024 (nIter=8), grid zb*128
    gemm256<<<dim3(zb * 4 * 32), 512, 0, stream>>>(
        s, vt + (size_t)b0 * 2097152, pvp, 4096, 4096, 512, 8, 16, 2, 4,
        16777216, 1024, 2097152, 1024, 2097152);
    reduce4<<<dim3(1024, zb), 256, 0, stream>>>(pvp, o + (size_t)b0 * 2097152);
  }
  // out = x + Wp O^T + bp  -> [B,C,N] f32
  gemm_bt<3><<<dim3(4, 32, 8), 256, 0, stream>>>(
      wpb, o, d_out, 512, 512, 512, 4096, bp, x, 0, 2097152, 2097152, 2097152);
}

// Round 6
// 609.709 us; speedup vs baseline: 2.1774x; 1.0493x over previous
//
#include <hip/hip_runtime.h>

// AttentionBlock: GN(32) -> q,k,v 1x1 -> softmax(qk^T/sqrt(C)) v -> proj + residual
// B=8, C=512, N=4096. ALL GEMMs on gemm256 (256x256 8-phase counted-vmcnt,
// T1+T2+T3+T4+T5). Q,K fused into one [32768,1024] GEMM; V proj batched;
// final proj computed as O*Wp^T (token-major) so resid/out are float4-vectorized.
// PV is K-split x4 with bf16 partials + reduce.

typedef __attribute__((ext_vector_type(8))) __bf16 bf16x8;
typedef __attribute__((ext_vector_type(4))) float f32x4;
typedef unsigned int u32;

#define DEVICE __device__ __forceinline__

DEVICE void async_copy16(const void* g, void* l) {
  __builtin_amdgcn_global_load_lds(
      (__attribute__((address_space(1))) u32*)(g),
      (__attribute__((address_space(3))) u32*)(l),
      16, 0, 0);
}

// ---------------------------------------------------------------- weights->bf16
__global__ __launch_bounds__(256) void cvt_w(
    const float* __restrict__ w0, const float* __restrict__ w1,
    const float* __restrict__ w2, const float* __restrict__ w3,
    __bf16* __restrict__ o0, __bf16* __restrict__ o1,
    __bf16* __restrict__ o2, __bf16* __restrict__ o3) {
  int idx = blockIdx.x * 256 + threadIdx.x;
  int off = idx * 8;
  int m = off >> 18;
  int r = off & 262143;
  const float* src = m == 0 ? w0 : m == 1 ? w1 : m == 2 ? w2 : w3;
  __bf16* dst = m == 0 ? o0 : m == 1 ? o1 : m == 2 ? o2 : o3;
  float4 a = *(const float4*)(src + r);
  float4 b = *(const float4*)(src + r + 4);
  bf16x8 v = {(__bf16)a.x, (__bf16)a.y, (__bf16)a.z, (__bf16)a.w,
              (__bf16)b.x, (__bf16)b.y, (__bf16)b.z, (__bf16)b.w};
  *(bf16x8*)(dst + r) = v;
}

// ---------------------------------------------------------------- groupnorm stats
__global__ __launch_bounds__(256) void gn_stats(const float* __restrict__ x,
                                                float* __restrict__ stats) {
  int bg = blockIdx.x;
  const float* p = x + (size_t)bg * 65536;
  int t = threadIdx.x, lane = t & 63, w = t >> 6;
  float s = 0.f, ss = 0.f;
  for (int i = t; i < 16384; i += 256) {
    float4 v = *(const float4*)(p + i * 4);
    s += v.x + v.y + v.z + v.w;
    ss += v.x * v.x + v.y * v.y + v.z * v.z + v.w * v.w;
  }
#pragma unroll
  for (int off = 32; off; off >>= 1) {
    s += __shfl_xor(s, off);
    ss += __shfl_xor(ss, off);
  }
  __shared__ float rs_[4], rss_[4];
  if (lane == 0) { rs_[w] = s; rss_[w] = ss; }
  __syncthreads();
  if (t == 0) {
    float S = rs_[0] + rs_[1] + rs_[2] + rs_[3];
    float SS = rss_[0] + rss_[1] + rss_[2] + rss_[3];
    float mean = S * (1.0f / 65536.0f);
    float var = SS * (1.0f / 65536.0f) - mean * mean;
    stats[bg * 2] = mean;
    stats[bg * 2 + 1] = rsqrtf(var + 1e-5f);
  }
}

// ---------------------------------------------------------------- groupnorm apply + transpose to [B,N,C] bf16
__global__ __launch_bounds__(256) void gn_apply(
    const float* __restrict__ x, const float* __restrict__ gamma,
    const float* __restrict__ beta, const float* __restrict__ stats,
    __bf16* __restrict__ h) {
  int b = blockIdx.z, g = blockIdx.y;
  int n = blockIdx.x * 256 + threadIdx.x;
  const float* px = x + ((size_t)b * 512 + g * 16) * 4096 + n;
  float mean = stats[(b * 32 + g) * 2];
  float rstd = stats[(b * 32 + g) * 2 + 1];
  bf16x8 lo, hi;
#pragma unroll
  for (int c = 0; c < 8; ++c) {
    float v = px[(size_t)c * 4096];
    lo[c] = (__bf16)((v - mean) * rstd * gamma[g * 16 + c] + beta[g * 16 + c]);
  }
#pragma unroll
  for (int c = 0; c < 8; ++c) {
    float v = px[(size_t)(c + 8) * 4096];
    hi[c] = (__bf16)((v - mean) * rstd * gamma[g * 16 + c + 8] + beta[g * 16 + c + 8]);
  }
  __bf16* dst = h + ((size_t)b * 4096 + n) * 512 + g * 16;
  *(bf16x8*)dst = lo;
  *(bf16x8*)(dst + 8) = hi;
}

// ---------------------------------------------------------------- gemm256: 256x256 8-phase template
// C[m,n] = sum_k A[m,k]*B[n,k]. 512 thr = 8 waves (2M x 4N), BK=64, LDS 128 KiB dbuf.
// Counted vmcnt(4) at phases 3/7 (T4); setprio around MFMA (T5); chunk^=(row&7)
// both-sides swizzle (T2, rule #21); bijective XCD swizzle (T1).
// EPI: 0 plain bf16 | 1 bf16 + 2-ptr colbias (QK fused) | 2 bf16 + rowbias (V)
//      3 f32 token-major: out[(row>>12)*512+col][row&4095] = acc+bias0[col]+resid, float4

#define G256_PHASE(BUF, QR, QC, RDA, RDB, STAGE_STMT, TAIL_STMT)               \
  do {                                                                         \
    if (RDA) {                                                                 \
      _Pragma("unroll") for (int fr = 0; fr < 4; ++fr) {                       \
        a[fr][0] = ldA(BUF, (QR)*4 + fr, 0);                                   \
        a[fr][1] = ldA(BUF, (QR)*4 + fr, 1);                                   \
      }                                                                        \
    }                                                                          \
    if (RDB) {                                                                 \
      _Pragma("unroll") for (int fc = 0; fc < 2; ++fc) {                       \
        b[(QC)*2 + fc][0] = ldB(BUF, (QC)*2 + fc, 0);                          \
        b[(QC)*2 + fc][1] = ldB(BUF, (QC)*2 + fc, 1);                          \
      }                                                                        \
    }                                                                          \
    STAGE_STMT;                                                                \
    __builtin_amdgcn_s_barrier();                                              \
    asm volatile("s_waitcnt lgkmcnt(0)" ::: "memory");                         \
    __builtin_amdgcn_sched_barrier(0);                                         \
    __builtin_amdgcn_s_setprio(1);                                             \
    _Pragma("unroll") for (int fr = 0; fr < 4; ++fr)                           \
      _Pragma("unroll") for (int fc = 0; fc < 2; ++fc) {                       \
        acc[(QR)*4 + fr][(QC)*2 + fc] =                                        \
            __builtin_amdgcn_mfma_f32_16x16x32_bf16(                           \
                a[fr][0], b[(QC)*2 + fc][0], acc[(QR)*4 + fr][(QC)*2 + fc],    \
                0, 0, 0);                                                      \
        acc[(QR)*4 + fr][(QC)*2 + fc] =                                        \
            __builtin_amdgcn_mfma_f32_16x16x32_bf16(                           \
                a[fr][1], b[(QC)*2 + fc][1], acc[(QR)*4 + fr][(QC)*2 + fc],    \
                0, 0, 0);                                                      \
      }                                                                        \
    __builtin_amdgcn_s_setprio(0);                                             \
    TAIL_STMT;                                                                 \
    __builtin_amdgcn_sched_barrier(0);                                         \
    __builtin_amdgcn_s_barrier();                                              \
  } while (0)

#define G256_ITER(T0, T1, LAST)                                                \
  G256_PHASE(0, 0, 0, 1, 1, stage(1, 0, 0, (T1)), ((void)0));                  \
  G256_PHASE(0, 0, 1, 0, 1, stage(1, 0, 1, (T1)), ((void)0));                  \
  G256_PHASE(0, 1, 0, 1, 0,                                                    \
             if (!(LAST)) stage(0, 1, 0, (T0) + 2), ((void)0));                \
  G256_PHASE(0, 1, 1, 0, 0,                                                    \
             if (!(LAST)) stage(0, 1, 1, (T0) + 2),                            \
             if (LAST) {                                                       \
               asm volatile("s_waitcnt vmcnt(0)" ::: "memory");                \
             } else {                                                          \
               asm volatile("s_waitcnt vmcnt(4)" ::: "memory");                \
             });                                                               \
  G256_PHASE(1, 0, 0, 1, 1,                                                    \
             if (!(LAST)) stage(0, 0, 0, (T0) + 2), ((void)0));                \
  G256_PHASE(1, 0, 1, 0, 1,                                                    \
             if (!(LAST)) stage(0, 0, 1, (T0) + 2), ((void)0));                \
  G256_PHASE(1, 1, 0, 1, 0,                                                    \
             if (!(LAST)) stage(1, 1, 0, (T1) + 2), ((void)0));                \
  G256_PHASE(1, 1, 1, 0, 0,                                                    \
             if (!(LAST)) stage(1, 1, 1, (T1) + 2),                            \
             if (!(LAST)) {                                                    \
               asm volatile("s_waitcnt vmcnt(4)" ::: "memory");                \
             })

template <int EPI>
__global__ __launch_bounds__(512, 2) void gemm256(
    const __bf16* __restrict__ A, const __bf16* __restrict__ B,
    void* __restrict__ CoutV, int lda, int ldb, int ldc, int nIter, int nTM,
    int nTN, int KS, long sA, long sKA, long sB, long sKB, long sC,
    const float* __restrict__ bias0, const float* __restrict__ bias1,
    const float* __restrict__ resid) {
  __shared__ __bf16 lds_raw[2][2][2][128][64];  // [buf][mat][half][row][k]

  int nwg = gridDim.x, bid = blockIdx.x;
  int qq = nwg >> 3, rr = nwg & 7;
  int xcd = bid & 7, ii = bid >> 3;
  int swz = (xcd < rr ? xcd * (qq + 1) : rr * (qq + 1) + (xcd - rr) * qq) + ii;
  int tn = swz % nTN;
  int tm = (swz / nTN) % nTM;
  int zz = swz / (nTN * nTM);
  int z = zz / KS, ks = zz % KS;
  A += (size_t)z * sA + (size_t)ks * sKA;
  B += (size_t)z * sB + (size_t)ks * sKB;
  __bf16* Cout = (__bf16*)CoutV + (size_t)zz * sC;
  int row0 = tm * 256, col0 = tn * 256;

  int tid = threadIdx.x;
  int wid = tid >> 6, lane = tid & 63;
  int wr = wid >> 2, wc = wid & 3;
  int l15 = lane & 15, l4 = lane >> 4;

  auto stage = [&](int buf, int mat, int half, int kt) {
    const __bf16* src = mat ? B : A;
    int ld = mat ? ldb : lda;
    int rbase = (mat ? col0 : row0) + half * 128;
    char* ldsbase = (char*)lds_raw + (((buf * 2 + mat) * 2 + half) * 16384);
#pragma unroll
    for (int L = 0; L < 2; ++L) {
      int ci = L * 512 + tid;
      int r = ci >> 3, cslot = ci & 7;
      int csrc = cslot ^ (r & 7);
      async_copy16(src + (size_t)(rbase + r) * ld + kt * 64 + csrc * 8,
                   ldsbase + (L * 512 + wid * 64) * 16);
    }
  };
  auto ldA = [&](int buf, int fr, int kh) -> bf16x8 {
    int row = fr * 16 + l15;
    int g = kh * 4 + l4;
    char* base = (char*)lds_raw + (((buf * 2 + 0) * 2 + wr) * 16384);
    return *(const bf16x8*)(base + row * 128 + ((g ^ (row & 7)) * 16));
  };
  auto ldB = [&](int buf, int fc, int kh) -> bf16x8 {
    int row = (wc & 1) * 64 + fc * 16 + l15;
    int g = kh * 4 + l4;
    char* base = (char*)lds_raw + (((buf * 2 + 1) * 2 + (wc >> 1)) * 16384);
    return *(const bf16x8*)(base + row * 128 + ((g ^ (row & 7)) * 16));
  };

  f32x4 acc[8][4] = {};
  bf16x8 a[4][2], b[4][2];

  stage(0, 1, 0, 0);
  stage(0, 1, 1, 0);
  stage(0, 0, 0, 0);
  stage(0, 0, 1, 0);
  stage(1, 1, 0, 1);
  stage(1, 1, 1, 1);
  asm volatile("s_waitcnt vmcnt(4)" ::: "memory");
  __builtin_amdgcn_sched_barrier(0);
  __builtin_amdgcn_s_barrier();

  int it = 0;
  for (; it < nIter - 1; ++it) {
    G256_ITER(2 * it, 2 * it + 1, 0);
  }
  G256_ITER(2 * it, 2 * it + 1, 1);

  // epilogue: C/D layout col=lane&15, row=(lane>>4)*4+rg [m89-verified]
  int rb = row0 + wr * 128, cb = col0 + wc * 64;
#pragma unroll
  for (int fr = 0; fr < 8; ++fr) {
#pragma unroll
    for (int fc = 0; fc < 4; ++fc) {
      int col = cb + fc * 16 + l15;
      if constexpr (EPI == 3) {
        // token-major f32: row = global token, col = channel
        int r0 = rb + fr * 16 + l4 * 4;
        size_t idx = ((size_t)(r0 >> 12) * 512 + col) * 4096 + (r0 & 4095);
        float4 rv = *(const float4*)(resid + idx);
        float bb = bias0[col];
        float4 ov = {acc[fr][fc][0] + bb + rv.x, acc[fr][fc][1] + bb + rv.y,
                     acc[fr][fc][2] + bb + rv.z, acc[fr][fc][3] + bb + rv.w};
        *(float4*)((float*)CoutV + idx) = ov;
      } else {
        float cbias = 0.f;
        if constexpr (EPI == 1)
          cbias = col < 512 ? bias0[col] : bias1[col - 512];
#pragma unroll
        for (int rg = 0; rg < 4; ++rg) {
          int row = rb + fr * 16 + l4 * 4 + rg;
          float v = acc[fr][fc][rg];
          if constexpr (EPI == 1) v += cbias;
          if constexpr (EPI == 2) v += bias0[row];
          Cout[(size_t)row * ldc + col] = (__bf16)v;
        }
      }
    }
  }
}

// ---------------------------------------------------------------- row softmax, in-place bf16 S -> bf16 P
__global__ __launch_bounds__(256) void softmax_rows_bf16(__bf16* __restrict__ S) {
  int row = blockIdx.x;
  __bf16* p = S + (size_t)row * 4096;
  int t = threadIdx.x, lane = t & 63, w = t >> 6;
  const float c1 = 0.04419417382415922f * 1.4426950408889634f;
  bf16x8 v0 = *(const bf16x8*)(p + t * 16);
  bf16x8 v1 = *(const bf16x8*)(p + t * 16 + 8);
  float f[16];
  float mx = -3.4e38f;
#pragma unroll
  for (int i = 0; i < 8; ++i) { f[i] = (float)v0[i]; mx = fmaxf(mx, f[i]); }
#pragma unroll
  for (int i = 0; i < 8; ++i) { f[8 + i] = (float)v1[i]; mx = fmaxf(mx, f[8 + i]); }
#pragma unroll
  for (int off = 32; off; off >>= 1) mx = fmaxf(mx, __shfl_xor(mx, off));
  __shared__ float rm[4], rsum[4];
  if (lane == 0) rm[w] = mx;
  __syncthreads();
  float m = fmaxf(fmaxf(rm[0], rm[1]), fmaxf(rm[2], rm[3]));
  float s = 0.f;
#pragma unroll
  for (int i = 0; i < 16; ++i) {
    f[i] = exp2f((f[i] - m) * c1);
    s += f[i];
  }
#pragma unroll
  for (int off = 32; off; off >>= 1) s += __shfl_xor(s, off);
  if (lane == 0) rsum[w] = s;
  __syncthreads();
  float inv = 1.0f / (rsum[0] + rsum[1] + rsum[2] + rsum[3]);
  bf16x8 o0, o1;
#pragma unroll
  for (int i = 0; i < 8; ++i) o0[i] = (__bf16)(f[i] * inv);
#pragma unroll
  for (int i = 0; i < 8; ++i) o1[i] = (__bf16)(f[8 + i] * inv);
  *(bf16x8*)(p + t * 16) = o0;
  *(bf16x8*)(p + t * 16 + 8) = o1;
}

// ---------------------------------------------------------------- sum 4 K-split partials -> O
__global__ __launch_bounds__(256) void reduce4(const __bf16* __restrict__ part,
                                               __bf16* __restrict__ out) {
  int z = blockIdx.y;
  size_t e = ((size_t)blockIdx.x * 256 + threadIdx.x) * 8;
  const __bf16* p = part + (size_t)z * 4 * 2097152 + e;
  bf16x8 v0 = *(const bf16x8*)(p);
  bf16x8 v1 = *(const bf16x8*)(p + 2097152);
  bf16x8 v2 = *(const bf16x8*)(p + 2 * 2097152);
  bf16x8 v3 = *(const bf16x8*)(p + 3 * 2097152);
  bf16x8 o;
#pragma unroll
  for (int j = 0; j < 8; ++j)
    o[j] = (__bf16)((float)v0[j] + (float)v1[j] + (float)v2[j] + (float)v3[j]);
  *(bf16x8*)(out + (size_t)z * 2097152 + e) = o;
}

// ---------------------------------------------------------------- launch
extern "C" void kernel_launch(void* const* d_in, const int* in_sizes, int n_in,
                              void* d_out, int out_size, void* d_ws, size_t ws_size,
                              hipStream_t stream) {
  const float* x = (const float*)d_in[0];
  const float* gamma = (const float*)d_in[1];
  const float* beta = (const float*)d_in[2];
  const float* wq = (const float*)d_in[3];
  const float* bq = (const float*)d_in[4];
  const float* wk = (const float*)d_in[5];
  const float* bk = (const float*)d_in[6];
  const float* wv = (const float*)d_in[7];
  const float* bv = (const float*)d_in[8];
  const float* wp = (const float*)d_in[9];
  const float* bp = (const float*)d_in[10];

  char* p = (char*)d_ws;
  auto alloc = [&](size_t bytes) {
    char* r = p;
    p += (bytes + 255) & ~(size_t)255;
    return r;
  };
  float* stats = (float*)alloc(256 * 2 * 4);
  __bf16* wqkb = (__bf16*)alloc((size_t)1024 * 512 * 2);    // [Wq; Wk]
  __bf16* wvb = (__bf16*)alloc(512 * 512 * 2);
  __bf16* wpb = (__bf16*)alloc(512 * 512 * 2);
  __bf16* ho = (__bf16*)alloc((size_t)8 * 4096 * 512 * 2);  // h, later aliased as O
  __bf16* qk = (__bf16*)alloc((size_t)8 * 4096 * 1024 * 2); // [B*N, 1024] Q|K
  __bf16* vt = (__bf16*)alloc((size_t)8 * 512 * 4096 * 2);  // [B, C, N]

  // per-chunk: S bf16 (32 MiB/b) + PV partials (16 MiB/b)
  const size_t SB = (size_t)4096 * 4096 * 2;
  const size_t PB = (size_t)4 * 4096 * 512 * 2;
  size_t used = (size_t)(p - (char*)d_ws);
  size_t freeb = (ws_size > used) ? ws_size - used : 0;
  int nb = (int)(freeb / (SB + PB));
  if (nb > 8) nb = 8;
  if (nb < 1) nb = 1;
  __bf16* s = (__bf16*)alloc(SB * nb);
  __bf16* pvp = (__bf16*)alloc(PB * nb);

  cvt_w<<<512, 256, 0, stream>>>(wq, wk, wv, wp, wqkb, wqkb + 262144, wvb, wpb);
  gn_stats<<<256, 256, 0, stream>>>(x, stats);
  gn_apply<<<dim3(16, 32, 8), 256, 0, stream>>>(x, gamma, beta, stats, ho);

  // QK fused: [32768,1024] = h x [Wq;Wk]^T + colbias2. grid 128*4 = 512
  gemm256<1><<<dim3(512), 512, 0, stream>>>(
      ho, wqkb, qk, 512, 512, 1024, 4, 128, 4, 1, 0, 0, 0, 0, 0, bq, bk, nullptr);
  // Vt[b] = Wv h[b]^T + rowbias. M=512,N=4096,z=8 -> grid 256
  gemm256<2><<<dim3(256), 512, 0, stream>>>(
      wvb, ho, vt, 512, 512, 4096, 4, 2, 16, 1, 0, 0, 2097152, 0, 2097152,
      bv, nullptr, nullptr);

  __bf16* o = ho;  // h dead after V proj -> O aliases it
  for (int b0 = 0; b0 < 8; b0 += nb) {
    int zb = (8 - b0 < nb) ? (8 - b0) : nb;
    // S = Q K^T: A = qk (cols 0..511), B = qk+512 (cols 512..1023), lda/ldb=1024
    gemm256<0><<<dim3(zb * 256), 512, 0, stream>>>(
        qk + (size_t)b0 * 4194304, qk + (size_t)b0 * 4194304 + 512, s, 1024,
        1024, 4096, 4, 16, 16, 1, 4194304, 0, 4194304, 0, 16777216,
        nullptr, nullptr, nullptr);
    softmax_rows_bf16<<<zb * 4096, 256, 0, stream>>>(s);
    // partial O = P V, K-split x4: M=4096,N=512,Ksub=1024 -> grid zb*128
    gemm256<0><<<dim3(zb * 128), 512, 0, stream>>>(
        s, vt + (size_t)b0 * 2097152, pvp, 4096, 4096, 512, 8, 16, 2, 4,
        16777216, 1024, 2097152, 1024, 2097152, nullptr, nullptr, nullptr);
    reduce4<<<dim3(1024, zb), 256, 0, stream>>>(pvp, o + (size_t)b0 * 2097152);
  }
  // out[b,c,n] = x + O Wp^T + bp (token-major epilogue, float4 resid+store)
  gemm256<3><<<dim3(256), 512, 0, stream>>>(
      o, wpb, d_out, 512, 512, 0, 4, 128, 2, 1, 0, 0, 0, 0, 0, bp, nullptr, x);
}